// Round 7
// baseline (446.878 us; speedup 1.0000x reference)
//
#include <hip/hip_runtime.h>
#include <math.h>

#define N_NODES 50000
#define N_EDGES 300000
#define BN_EPS 1e-5f
#define NEG_SLOPE 0.2f

// 50000 rows pad to 3128 row-blocks of 16 (50048)
#define RB_COUNT 3128
#define SCAN_TILES 49    // 49*1024 = 50176 >= N_NODES
#define BN1_BLOCKS 523   // 523*96 = 50208 >= N_NODES
#define K5_BLOCKS 1024

// persistent aggregation grid: 8 blocks/CU x 256 CUs, 4 waves/block
#define AGG_BLOCKS 2048
#define AGG_STRIDE (AGG_BLOCKS * 4)

// prep kernel block ranges
#define PREP_BN0 128
#define PREP_EC  1172    // (300000+255)/256
#define PREP_PW  128

typedef short bf8v __attribute__((ext_vector_type(8)));
typedef float f4v __attribute__((ext_vector_type(4)));
typedef float f2v __attribute__((ext_vector_type(2)));

__device__ inline unsigned short f2bf(float f) {
    union { float f; unsigned u; } c; c.f = f;
    unsigned r = c.u + 0x7fffu + ((c.u >> 16) & 1u);
    return (unsigned short)(r >> 16);
}

__device__ inline unsigned f2bf2(float lo, float hi) {
    return (unsigned)f2bf(lo) | ((unsigned)f2bf(hi) << 16);
}

// unpack 2 bf16 (one dword) -> float2; lo -> .x, hi -> .y
__device__ inline f2v bfpair(unsigned u) {
    union { unsigned u; float f; } lo, hi;
    lo.u = u << 16;
    hi.u = u & 0xffff0000u;
    f2v r; r.x = lo.f; r.y = hi.f;
    return r;
}

// async global->LDS DMA, 16B per lane; LDS dest = ldsbase + lane*16 (wave-uniform base)
__device__ inline void async_copy16(void* lds, const void* g) {
    __builtin_amdgcn_global_load_lds(
        (const __attribute__((address_space(1))) unsigned int*)g,
        (__attribute__((address_space(3))) unsigned int*)lds, 16, 0, 0);
}

// ---------------- prep: BN0 stats | edge_count | pack_w (independent, block-split) ------
__global__ __launch_bounds__(256) void prep(
        const float* __restrict__ h, float* __restrict__ acc,
        const int* __restrict__ dst, int* __restrict__ count,
        const float* __restrict__ Wl0, const float* __restrict__ Wr0,
        const float* __restrict__ Wl1, const float* __restrict__ Wr1,
        unsigned short* __restrict__ bp) {
    int b = blockIdx.x;
    if (b < PREP_BN0) {
        // ---- BN0 column stats ----
        __shared__ float lds[4][10];
        int tid = threadIdx.x;
        int lane = tid & 63, wave = tid >> 6;
        float ls[5] = {0,0,0,0,0}, lq[5] = {0,0,0,0,0};
        for (int r = b * 256 + tid; r < N_NODES; r += PREP_BN0 * 256) {
            #pragma unroll
            for (int k = 0; k < 5; k++) {
                float v = h[r*5 + k];
                ls[k] += v; lq[k] += v*v;
            }
        }
        #pragma unroll
        for (int k = 0; k < 5; k++) {
            #pragma unroll
            for (int m = 1; m <= 32; m <<= 1) {
                ls[k] += __shfl_xor(ls[k], m, 64);
                lq[k] += __shfl_xor(lq[k], m, 64);
            }
        }
        if (lane == 0) {
            #pragma unroll
            for (int k = 0; k < 5; k++) { lds[wave][k] = ls[k]; lds[wave][5+k] = lq[k]; }
        }
        __syncthreads();
        if (tid < 10) {
            float s = lds[0][tid] + lds[1][tid] + lds[2][tid] + lds[3][tid];
            atomicAdd(&acc[tid], s);
        }
    } else if (b < PREP_BN0 + PREP_EC) {
        // ---- edge histogram by dst ----
        int e = (b - PREP_BN0) * 256 + threadIdx.x;
        if (e < N_EDGES) atomicAdd(&count[dst[e]], 1);
    } else {
        // ---- pack mu/ls weights -> bf16 MFMA B-fragment order ----
        int t = (b - PREP_BN0 - PREP_EC) * 256 + threadIdx.x;   // 32768 threads exact
        int lane = t & 63;
        int nt = (t >> 6) & 31;
        int kc = (t >> 11) & 7;
        int conv = t >> 14;
        int col = nt * 16 + (lane & 15);
        int k0 = kc * 32 + (lane >> 4) * 8;
        const float* W = conv ? (col < 256 ? Wl1 : Wr1) : (col < 256 ? Wl0 : Wr0);
        int c = col & 255;
        union { unsigned short h[8]; uint4 u; } tmp;
        #pragma unroll
        for (int j = 0; j < 8; j++) tmp.h[j] = f2bf(W[(size_t)(k0 + j) * 256 + c]);
        *reinterpret_cast<uint4*>(bp + (size_t)t * 8) = tmp.u;
    }
}

// ---------------- CSR scan: wave-shfl local scan (2 barriers) ----------------
__global__ void local_scan(const int* __restrict__ count, int* __restrict__ offsets,
                           int* __restrict__ tileSum) {
    __shared__ int wsum[16];
    int tid = threadIdx.x;
    int lane = tid & 63, wv = tid >> 6;
    int i = blockIdx.x * 1024 + tid;
    int v = (i < N_NODES) ? count[i] : 0;
    int inc = v;
    #pragma unroll
    for (int off = 1; off < 64; off <<= 1) {
        int t = __shfl_up(inc, off, 64);
        if (lane >= off) inc += t;
    }
    if (lane == 63) wsum[wv] = inc;
    __syncthreads();
    if (wv == 0) {
        int val = (lane < 16) ? wsum[lane] : 0;
        int inc2 = val;
        #pragma unroll
        for (int off = 1; off < 16; off <<= 1) {
            int t = __shfl_up(inc2, off, 64);
            if (lane >= off) inc2 += t;
        }
        if (lane < 16) wsum[lane] = inc2 - val;   // exclusive wave prefix
    }
    __syncthreads();
    int excl = inc - v + wsum[wv];
    if (i < N_NODES) offsets[i] = excl;           // local exclusive
    if (tid == 1023) tileSum[blockIdx.x] = excl + v;
}

// add_prefix with fused tile-prefix computation (each block wave-reduces its prefix)
__global__ void add_prefix(int* __restrict__ offsets, const int* __restrict__ tileSum,
                           int* __restrict__ cursor) {
    __shared__ int spref;
    int tid = threadIdx.x;
    if (tid < 64) {
        int v = (tid < blockIdx.x) ? tileSum[tid] : 0;   // blockIdx.x <= 48 < 64
        #pragma unroll
        for (int m = 1; m <= 32; m <<= 1) v += __shfl_xor(v, m, 64);
        if (tid == 0) spref = v;
    }
    __syncthreads();
    int i = blockIdx.x * 1024 + tid;
    if (i < N_NODES) {
        int o = offsets[i] + spref;
        offsets[i] = o;
        cursor[i] = o;
    }
    if (blockIdx.x == 0 && tid == 0) offsets[N_NODES] = N_EDGES;  // total is constant
}

// scatter edges into CSR order as packed (src, edge-weight) int2
__global__ void edge_scatter(const int* __restrict__ dst, const int* __restrict__ src,
                             const float* __restrict__ ew, int* __restrict__ cursor,
                             int2* __restrict__ sep) {
    int e = blockIdx.x * blockDim.x + threadIdx.x;
    if (e < N_EDGES) {
        int pos = atomicAdd(&cursor[dst[e]], 1);
        sep[pos] = make_int2(src[e], __float_as_int(ew[e]));
    }
}

// ---------------- conv1 linear (K=5), fused BN0 finalize+apply, reg-resident weights ----
__global__ __launch_bounds__(128) void gemm_k5(const float* __restrict__ h,
        const float* __restrict__ acc10, const float* __restrict__ g5,
        const float* __restrict__ b5,
        const float* __restrict__ Wl, const float* __restrict__ bl,
        const float* __restrict__ Wr, const float* __restrict__ br,
        unsigned short* __restrict__ xl, unsigned short* __restrict__ xr) {
    int c = threadIdx.x * 2;
    float sc[5], sh[5];
    #pragma unroll
    for (int k = 0; k < 5; k++) {
        float mean = acc10[k] * (1.f / N_NODES);
        float var  = acc10[5 + k] * (1.f / N_NODES) - mean * mean;
        float s = g5[k] * rsqrtf(var + BN_EPS);
        sc[k] = s; sh[k] = b5[k] - mean * s;
    }
    float wl0[5], wl1[5], wr0[5], wr1[5];
    #pragma unroll
    for (int k = 0; k < 5; k++) {
        wl0[k] = Wl[k*256 + c]; wl1[k] = Wl[k*256 + c + 1];
        wr0[k] = Wr[k*256 + c]; wr1[k] = Wr[k*256 + c + 1];
    }
    float bl0 = bl[c], bl1 = bl[c+1], br0 = br[c], br1 = br[c+1];
    int n = blockIdx.x;
    float hv[5];
    if (n < N_NODES) {
        #pragma unroll
        for (int k = 0; k < 5; k++) hv[k] = h[n*5 + k];
    }
    for (; n < N_NODES; n += K5_BLOCKS) {
        int n2 = n + K5_BLOCKS;
        float hn[5] = {0,0,0,0,0};
        if (n2 < N_NODES) {
            #pragma unroll
            for (int k = 0; k < 5; k++) hn[k] = h[n2*5 + k];
        }
        float l0 = bl0, l1 = bl1, r0 = br0, r1 = br1;
        #pragma unroll
        for (int k = 0; k < 5; k++) {
            float a = hv[k] * sc[k] + sh[k];
            l0 += a * wl0[k]; l1 += a * wl1[k];
            r0 += a * wr0[k]; r1 += a * wr1[k];
        }
        *reinterpret_cast<unsigned*>(xl + (size_t)n*256 + c) = f2bf2(l0, l1);
        *reinterpret_cast<unsigned*>(xr + (size_t)n*256 + c) = f2bf2(r0, r1);
        #pragma unroll
        for (int k = 0; k < 5; k++) hv[k] = hn[k];
    }
}

// ---------------- big linear via MFMA: BN1+ReLU fused A-load, ONE conv per block --------
// grid 1564: blocks [0,782) -> conv A (mu), [782,1564) -> conv B (ls).
// OPERAND-SWAPPED MFMA: acc holds C^T fragments -> each lane owns node row (lane&15)
// and 4 CONSECUTIVE output cols (reg 0..3) -> packed 8B C-stores (16 instead of 64x2B).
__global__ __launch_bounds__(512, 4) void gemm_mfma(const unsigned short* __restrict__ xh,
        const float* __restrict__ ss1,
        const unsigned short* __restrict__ bp,
        const float* __restrict__ bl0, const float* __restrict__ br0,
        const float* __restrict__ bl1, const float* __restrict__ br1,
        unsigned short* __restrict__ xlA, unsigned short* __restrict__ xrA,
        unsigned short* __restrict__ xlB, unsigned short* __restrict__ xrB) {
    __shared__ unsigned short Bs[2][32][512];   // [buf][frag f=h*16+t][lane*8]
    int cv = blockIdx.x >= 782;
    int bb = cv ? blockIdx.x - 782 : blockIdx.x;
    int lane = threadIdx.x & 63;
    int wave = threadIdx.x >> 6;
    int h = wave & 1;
    int rb = bb * 4 + (wave >> 1);

    const unsigned short* bsrc = bp + (size_t)cv * 131072 + lane * 8;
    auto stage = [&](int buf, int kc) {
        #pragma unroll
        for (int j = 0; j < 4; j++) {
            int f = wave * 4 + j;
            async_copy16(&Bs[buf][f][lane * 8], bsrc + (size_t)kc * 16384 + f * 512);
        }
    };
    stage(0, 0);

    // ---- load A fragments from xBh with fused BN1 scale/shift + ReLU -> bf16 ----
    int row = rb * 16 + (lane & 15);
    int k0b = (lane >> 4) * 8;
    bool rok = row < N_NODES;
    bf8v a[8];
    #pragma unroll
    for (int kc = 0; kc < 8; kc++) {
        int k0 = kc * 32 + k0b;
        union { unsigned short hh[8]; uint4 u; bf8v v; } tmp;
        if (rok) {
            uint4 u = *(const uint4*)(xh + (size_t)row * 256 + k0);
            f4v s0 = *(const f4v*)(ss1 + k0);
            f4v s1 = *(const f4v*)(ss1 + k0 + 4);
            f4v h0 = *(const f4v*)(ss1 + 256 + k0);
            f4v h1 = *(const f4v*)(ss1 + 256 + k0 + 4);
            float f[8];
            f2v p;
            p = bfpair(u.x); f[0] = p.x; f[1] = p.y;
            p = bfpair(u.y); f[2] = p.x; f[3] = p.y;
            p = bfpair(u.z); f[4] = p.x; f[5] = p.y;
            p = bfpair(u.w); f[6] = p.x; f[7] = p.y;
            float scv[8] = {s0.x, s0.y, s0.z, s0.w, s1.x, s1.y, s1.z, s1.w};
            float shv[8] = {h0.x, h0.y, h0.z, h0.w, h1.x, h1.y, h1.z, h1.w};
            #pragma unroll
            for (int j = 0; j < 8; j++) {
                float v = f[j] * scv[j] + shv[j];
                v = v > 0.f ? v : 0.f;
                tmp.hh[j] = f2bf(v);
            }
        } else {
            tmp.u = (uint4){0u, 0u, 0u, 0u};
        }
        a[kc] = tmp.v;
    }

    f4v acc[16];
    #pragma unroll
    for (int t = 0; t < 16; t++) acc[t] = (f4v){0.f, 0.f, 0.f, 0.f};

    for (int kc = 0; kc < 8; kc++) {
        __syncthreads();                 // staging of buf kc&1 done; prev buf free
        if (kc < 7) stage((kc + 1) & 1, kc + 1);
        const unsigned short* bb2 = &Bs[kc & 1][h * 16][lane * 8];
        #pragma unroll
        for (int t = 0; t < 16; t++) {
            bf8v b = *reinterpret_cast<const bf8v*>(bb2 + t * 512);
            // swapped operands: acc[t] = C^T fragment
            acc[t] = __builtin_amdgcn_mfma_f32_16x16x32_bf16(b, a[kc], acc[t], 0, 0, 0);
        }
    }

    // ---- C^T epilogue: lane owns node row (lane&15), cols q*4..q*4+3 within each t ----
    int q = lane >> 4;
    unsigned short* outp = cv ? (h ? xrB : xlB) : (h ? xrA : xlA);
    const float* bias = cv ? (h ? br1 : bl1) : (h ? br0 : bl0);
    if (rok) {
        unsigned short* orow = outp + (size_t)row * 256 + q * 4;
        #pragma unroll
        for (int t = 0; t < 16; t++) {
            f4v bv = *(const f4v*)(bias + t * 16 + q * 4);
            uint2 u;
            u.x = f2bf2(acc[t][0] + bv.x, acc[t][1] + bv.y);
            u.y = f2bf2(acc[t][2] + bv.z, acc[t][3] + bv.w);
            *reinterpret_cast<uint2*>(orow + t * 16) = u;
        }
    }
}

// ---------------- fused GATv2 edge phase (concat conv1), persistent waves ----------
// 2048 blocks x 4 waves; each wave grid-strides nodes (stride 8192). Per node:
// TWO edge streams (lanes 0-31 even, 32-63 odd), NO-MAX softmax, 2-deep pipeline.
__global__ __launch_bounds__(256) void agg_concat(
        const unsigned short* __restrict__ xl, const unsigned short* __restrict__ xr,
        const float* __restrict__ We, const float* __restrict__ att,
        const int* __restrict__ offsets, const int2* __restrict__ sep,
        const float* __restrict__ bias,
        unsigned short* __restrict__ outh) {
    int gw = blockIdx.x * 4 + (threadIdx.x >> 6);
    int lane = threadIdx.x & 63;
    int half = lane >> 5;
    int sub  = lane & 31;
    int cb   = (sub >> 4) * 128 + (sub & 15) * 8;
    f2v wv[4], av[4];
    float bs[8];
    {
        f4v t0 = *(const f4v*)(We + cb);
        f4v t1 = *(const f4v*)(We + cb + 4);
        wv[0] = (f2v){t0.x, t0.y}; wv[1] = (f2v){t0.z, t0.w};
        wv[2] = (f2v){t1.x, t1.y}; wv[3] = (f2v){t1.z, t1.w};
        t0 = *(const f4v*)(att + cb);
        t1 = *(const f4v*)(att + cb + 4);
        av[0] = (f2v){t0.x, t0.y}; av[1] = (f2v){t0.z, t0.w};
        av[2] = (f2v){t1.x, t1.y}; av[3] = (f2v){t1.z, t1.w};
        t0 = *(const f4v*)(bias + cb);
        t1 = *(const f4v*)(bias + cb + 4);
        bs[0]=t0.x; bs[1]=t0.y; bs[2]=t0.z; bs[3]=t0.w;
        bs[4]=t1.x; bs[5]=t1.y; bs[6]=t1.z; bs[7]=t1.w;
    }
    int n = gw;
    int beg = 0, end = 0;
    if (n < N_NODES) { beg = offsets[n]; end = offsets[n + 1]; }
    while (n < N_NODES) {
        int nn = n + AGG_STRIDE;
        int nbeg = 0, nend = 0;
        if (nn < N_NODES) { nbeg = offsets[nn]; nend = offsets[nn + 1]; }  // prefetch
        uint4 r8 = *(const uint4*)(xr + ((size_t)n << 8) + cb);
        f2v rv[4];
        rv[0] = bfpair(r8.x); rv[1] = bfpair(r8.y);
        rv[2] = bfpair(r8.z); rv[3] = bfpair(r8.w);

        float den = 0.f;
        f2v acc[4];
        #pragma unroll
        for (int j = 0; j < 4; j++) acc[j] = (f2v){0.f, 0.f};

        int i = beg + half;
        float wN = 0.f;
        int2 seP = make_int2(0, 0);
        uint4 lN = {0u, 0u, 0u, 0u};
        if (i < end) {
            int2 se = sep[i];
            wN = __int_as_float(se.y);
            lN = *(const uint4*)(xl + ((size_t)se.x << 8) + cb);
        }
        if (i + 2 < end) seP = sep[i + 2];
        for (; i < end; i += 2) {
            uint4 l8 = lN; float w = wN;
            if (i + 2 < end) {                           // gather uses pre-fetched index
                lN = *(const uint4*)(xl + ((size_t)seP.x << 8) + cb);
                wN = __int_as_float(seP.y);
            }
            if (i + 4 < end) seP = sep[i + 4];
            f2v w2 = (f2v){w, w};
            f2v lv[4];
            lv[0] = bfpair(l8.x); lv[1] = bfpair(l8.y);
            lv[2] = bfpair(l8.z); lv[3] = bfpair(l8.w);
            f2v da = (f2v){0.f, 0.f};
            #pragma unroll
            for (int j = 0; j < 4; j++) {
                f2v v = lv[j] + rv[j] + w2 * wv[j];
                f2v s = v * (f2v){NEG_SLOPE, NEG_SLOPE};
                v.x = fmaxf(v.x, s.x); v.y = fmaxf(v.y, s.y);   // leaky relu
                da += v * av[j];
            }
            float a = da.x + da.y;
            a += __shfl_xor(a, 1, 64);
            a += __shfl_xor(a, 2, 64);
            a += __shfl_xor(a, 4, 64);
            a += __shfl_xor(a, 8, 64);                   // per-head alpha (16-lane groups)
            float p = __expf(a);
            den += p;
            f2v p2 = (f2v){p, p};
            #pragma unroll
            for (int j = 0; j < 4; j++) acc[j] += p2 * lv[j];
        }
        // merge even/odd streams (pure adds)
        den += __shfl_xor(den, 32, 64);
        #pragma unroll
        for (int j = 0; j < 4; j++) {
            f2v ao;
            ao.x = __shfl_xor(acc[j].x, 32, 64);
            ao.y = __shfl_xor(acc[j].y, 32, 64);
            acc[j] += ao;
        }
        float inv = 1.f / (den + 1e-16f);
        if (lane < 32) {
            union { unsigned short hh[8]; uint4 u; } o;
            #pragma unroll
            for (int j = 0; j < 4; j++) {
                o.hh[2*j]   = f2bf(acc[j].x * inv + bs[2*j]);
                o.hh[2*j+1] = f2bf(acc[j].y * inv + bs[2*j + 1]);
            }
            *(uint4*)(outh + (size_t)n * 256 + cb) = o.u;
        }
        n = nn; beg = nbeg; end = nend;
    }
}

// ---------------- fused DUAL GATv2 edge phase (mu + log_std), persistent waves ----------
// CONV-PER-LANE-HALF: lanes 0-31 own conv A (mu), lanes 32-63 own conv B (ls).
// Single shared edge stream; one gather instruction covers both tables; the
// shfl alpha-reduce serves both convs at once. Per-lane state halved -> VGPR<=64.
__global__ __launch_bounds__(256, 8) void agg_dual(
        const unsigned short* __restrict__ xlA, const unsigned short* __restrict__ xrA,
        const unsigned short* __restrict__ xlB, const unsigned short* __restrict__ xrB,
        const float* __restrict__ WeA, const float* __restrict__ attA,
        const float* __restrict__ WeB, const float* __restrict__ attB,
        const int* __restrict__ offsets, const int2* __restrict__ sep,
        const float* __restrict__ biasA, const float* __restrict__ biasB,
        float* __restrict__ outA, float* __restrict__ outB) {
    int gw = blockIdx.x * 4 + (threadIdx.x >> 6);
    int lane = threadIdx.x & 63;
    int sub  = lane & 31;
    int cb   = (sub >> 4) * 128 + (sub & 15) * 8;   // channel base within conv
    int c0   = (lane & 15) * 8;
    int convB = lane >> 5;                           // 0 = mu, 1 = ls
    const unsigned short* xlp = (convB ? xlB : xlA) + cb;
    const unsigned short* xrp = (convB ? xrB : xrA) + cb;
    const float* Wep  = convB ? WeB : WeA;
    const float* attp = convB ? attB : attA;
    f2v wv[4], av[4];
    {
        f4v t0 = *(const f4v*)(Wep + cb);
        f4v t1 = *(const f4v*)(Wep + cb + 4);
        wv[0] = (f2v){t0.x, t0.y}; wv[1] = (f2v){t0.z, t0.w};
        wv[2] = (f2v){t1.x, t1.y}; wv[3] = (f2v){t1.z, t1.w};
        t0 = *(const f4v*)(attp + cb);
        t1 = *(const f4v*)(attp + cb + 4);
        av[0] = (f2v){t0.x, t0.y}; av[1] = (f2v){t0.z, t0.w};
        av[2] = (f2v){t1.x, t1.y}; av[3] = (f2v){t1.z, t1.w};
    }
    int n = gw;
    int beg = 0, end = 0;
    if (n < N_NODES) { beg = offsets[n]; end = offsets[n + 1]; }
    while (n < N_NODES) {
        int nn = n + AGG_STRIDE;
        int nbeg = 0, nend = 0;
        if (nn < N_NODES) { nbeg = offsets[nn]; nend = offsets[nn + 1]; }  // prefetch
        uint4 r8 = *(const uint4*)(xrp + ((size_t)n << 8));
        f2v rv[4];
        rv[0] = bfpair(r8.x); rv[1] = bfpair(r8.y);
        rv[2] = bfpair(r8.z); rv[3] = bfpair(r8.w);

        float den = 0.f;
        f2v acc[4];
        #pragma unroll
        for (int j = 0; j < 4; j++) acc[j] = (f2v){0.f, 0.f};

        int i = beg;
        float wN = 0.f, wP = 0.f;
        int sP = 0;
        uint4 lN = {0u, 0u, 0u, 0u};
        if (i < end) {
            int2 se = sep[i];
            wN = __int_as_float(se.y);
            lN = *(const uint4*)(xlp + ((size_t)se.x << 8));
        }
        if (i + 1 < end) { int2 se = sep[i + 1]; sP = se.x; wP = __int_as_float(se.y); }
        for (; i < end; ++i) {
            uint4 l8 = lN; float w = wN;
            if (i + 1 < end) {                           // gather uses pre-fetched index
                lN = *(const uint4*)(xlp + ((size_t)sP << 8));
                wN = wP;
            }
            if (i + 2 < end) { int2 se = sep[i + 2]; sP = se.x; wP = __int_as_float(se.y); }
            f2v w2 = (f2v){w, w};
            f2v lv[4];
            lv[0] = bfpair(l8.x); lv[1] = bfpair(l8.y);
            lv[2] = bfpair(l8.z); lv[3] = bfpair(l8.w);
            f2v da = (f2v){0.f, 0.f};
            #pragma unroll
            for (int j = 0; j < 4; j++) {
                f2v v = lv[j] + rv[j] + w2 * wv[j];
                f2v s = v * (f2v){NEG_SLOPE, NEG_SLOPE};
                v.x = fmaxf(v.x, s.x); v.y = fmaxf(v.y, s.y);   // leaky relu
                da += v * av[j];
            }
            float a = da.x + da.y;
            a += __shfl_xor(a, 1, 64);
            a += __shfl_xor(a, 2, 64);
            a += __shfl_xor(a, 4, 64);
            a += __shfl_xor(a, 8, 64);           // per-(conv,head) alpha (16-lane groups)
            float p = __expf(a);
            den += p;
            f2v p2 = (f2v){p, p};
            #pragma unroll
            for (int j = 0; j < 4; j++) acc[j] += p2 * lv[j];
        }
        float inv = 1.f / (den + 1e-16f);
        float o[8], po[8];
        #pragma unroll
        for (int j = 0; j < 4; j++) {
            o[2*j]   = acc[j].x * inv;
            o[2*j+1] = acc[j].y * inv;
        }
        #pragma unroll
        for (int j = 0; j < 8; j++) po[j] = __shfl_xor(o[j], 16, 64);  // other head
        int q = lane >> 4;
        if (q == 0) {                              // lanes 0-15 write conv A (mu)
            f4v b0 = *(const f4v*)(biasA + c0);
            f4v b1 = *(const f4v*)(biasA + c0 + 4);
            float r[8];
            r[0] = (o[0]+po[0])*0.5f + b0.x; r[1] = (o[1]+po[1])*0.5f + b0.y;
            r[2] = (o[2]+po[2])*0.5f + b0.z; r[3] = (o[3]+po[3])*0.5f + b0.w;
            r[4] = (o[4]+po[4])*0.5f + b1.x; r[5] = (o[5]+po[5])*0.5f + b1.y;
            r[6] = (o[6]+po[6])*0.5f + b1.z; r[7] = (o[7]+po[7])*0.5f + b1.w;
            *(float4*)(outA + (size_t)n * 128 + c0)     = *(float4*)&r[0];
            *(float4*)(outA + (size_t)n * 128 + c0 + 4) = *(float4*)&r[4];
        } else if (q == 2) {                       // lanes 32-47 write conv B (log_std)
            f4v b0 = *(const f4v*)(biasB + c0);
            f4v b1 = *(const f4v*)(biasB + c0 + 4);
            float r[8];
            r[0] = (o[0]+po[0])*0.5f + b0.x; r[1] = (o[1]+po[1])*0.5f + b0.y;
            r[2] = (o[2]+po[2])*0.5f + b0.z; r[3] = (o[3]+po[3])*0.5f + b0.w;
            r[4] = (o[4]+po[4])*0.5f + b1.x; r[5] = (o[5]+po[5])*0.5f + b1.y;
            r[6] = (o[6]+po[6])*0.5f + b1.z; r[7] = (o[7]+po[7])*0.5f + b1.w;
            *(float4*)(outB + (size_t)n * 128 + c0)     = *(float4*)&r[0];
            *(float4*)(outB + (size_t)n * 128 + c0 + 4) = *(float4*)&r[4];
        }
        n = nn; beg = nbeg; end = nend;
    }
}

// ---------------- BN1 stats, phase 1: per-block partials (bf16 input, NO atomics) --------
__global__ void bn1_reduce(const unsigned short* __restrict__ xh, float* __restrict__ part) {
    __shared__ float lds[256][9];   // stride 9 floats -> no bank conflicts
    int tid = threadIdx.x;
    int cg = tid & 63;              // col group: cols cg*4 .. cg*4+3
    int ph = tid >> 6;              // row phase 0..3
    int r0 = blockIdx.x * 96;
    float s[4] = {0,0,0,0}, q[4] = {0,0,0,0};
    #pragma unroll
    for (int it = 0; it < 24; it++) {
        int row = r0 + it * 4 + ph;
        if (row < N_NODES) {
            uint2 v = *(const uint2*)(xh + (size_t)row * 256 + cg * 4);
            f2v p0 = bfpair(v.x), p1 = bfpair(v.y);
            s[0] += p0.x; s[1] += p0.y; s[2] += p1.x; s[3] += p1.y;
            q[0] += p0.x*p0.x; q[1] += p0.y*p0.y; q[2] += p1.x*p1.x; q[3] += p1.y*p1.y;
        }
    }
    #pragma unroll
    for (int j = 0; j < 4; j++) { lds[tid][j] = s[j]; lds[tid][4+j] = q[j]; }
    __syncthreads();
    if (tid < 64) {
        float4 sv, qv;
        float* svp = (float*)&sv; float* qvp = (float*)&qv;
        #pragma unroll
        for (int j = 0; j < 4; j++) {
            svp[j] = lds[tid][j] + lds[tid+64][j] + lds[tid+128][j] + lds[tid+192][j];
            qvp[j] = lds[tid][4+j] + lds[tid+64][4+j] + lds[tid+128][4+j] + lds[tid+192][4+j];
        }
        *(float4*)(part + (size_t)blockIdx.x * 512 + cg * 4) = sv;
        *(float4*)(part + (size_t)blockIdx.x * 512 + 256 + cg * 4) = qv;
    }
}

__global__ void bn1_finalize(const float* __restrict__ part, const float* __restrict__ g,
                             const float* __restrict__ b, float* __restrict__ ss1) {
    __shared__ float lds[8][64];
    int t = threadIdx.x;
    int c = blockIdx.x * 32 + (t & 31);
    int ph = t >> 5;                 // 0..7
    float s = 0.f, q = 0.f;
    for (int bi = ph; bi < BN1_BLOCKS; bi += 8) {
        s += part[(size_t)bi * 512 + c];
        q += part[(size_t)bi * 512 + 256 + c];
    }
    lds[ph][t & 31] = s;
    lds[ph][32 + (t & 31)] = q;
    __syncthreads();
    if (t < 32) {
        float ss = 0.f, qq = 0.f;
        #pragma unroll
        for (int p = 0; p < 8; p++) { ss += lds[p][t]; qq += lds[p][32 + t]; }
        float mean = ss * (1.f / N_NODES);
        float var  = qq * (1.f / N_NODES) - mean * mean;
        float sc = g[c] * rsqrtf(var + BN_EPS);
        ss1[c] = sc;
        ss1[256 + c] = b[c] - mean * sc;
    }
}

extern "C" void kernel_launch(void* const* d_in, const int* in_sizes, int n_in,
                              void* d_out, int out_size, void* d_ws, size_t ws_size,
                              hipStream_t stream) {
    const float* h          = (const float*)d_in[0];
    const int*   edge_index = (const int*)d_in[1];
    const int*   src = edge_index;
    const int*   dst = edge_index + N_EDGES;
    const float* ew   = (const float*)d_in[2];
    const float* bn0g = (const float*)d_in[3];
    const float* bn0b = (const float*)d_in[4];
    const float* bn1g = (const float*)d_in[5];
    const float* bn1b = (const float*)d_in[6];
    const float* c1_Wl = (const float*)d_in[7];
    const float* c1_bl = (const float*)d_in[8];
    const float* c1_Wr = (const float*)d_in[9];
    const float* c1_br = (const float*)d_in[10];
    const float* c1_We = (const float*)d_in[11];
    const float* c1_att = (const float*)d_in[12];
    const float* c1_bias = (const float*)d_in[13];
    const float* mu_Wl = (const float*)d_in[14];
    const float* mu_bl = (const float*)d_in[15];
    const float* mu_Wr = (const float*)d_in[16];
    const float* mu_br = (const float*)d_in[17];
    const float* mu_We = (const float*)d_in[18];
    const float* mu_att = (const float*)d_in[19];
    const float* mu_bias = (const float*)d_in[20];
    const float* ls_Wl = (const float*)d_in[21];
    const float* ls_bl = (const float*)d_in[22];
    const float* ls_Wr = (const float*)d_in[23];
    const float* ls_br = (const float*)d_in[24];
    const float* ls_We = (const float*)d_in[25];
    const float* ls_att = (const float*)d_in[26];
    const float* ls_bias = (const float*)d_in[27];

    float* out_mu = (float*)d_out;
    float* out_ls = (float*)d_out + (size_t)N_NODES * 128;

    // workspace carve-up (256B aligned blocks)
    char* ws = (char*)d_ws;
    size_t off = 0;
    auto alloc = [&](size_t bytes) -> void* {
        void* p = ws + off;
        off += (bytes + 255) / 256 * 256;
        return p;
    };
    unsigned short* xl  = (unsigned short*)alloc((size_t)N_NODES * 256 * 2);
    unsigned short* xr  = (unsigned short*)alloc((size_t)N_NODES * 256 * 2);
    unsigned short* xBh = (unsigned short*)alloc((size_t)N_NODES * 256 * 2);  // bf16 conv1 out
    unsigned short* xl2 = (unsigned short*)alloc((size_t)N_NODES * 256 * 2);
    unsigned short* xr2 = (unsigned short*)alloc((size_t)N_NODES * 256 * 2);
    float* bn0acc  = (float*)alloc(10 * 4);
    float* bn1part = (float*)alloc((size_t)BN1_BLOCKS * 512 * 4);   // 1.07 MB
    float* bn1ss   = (float*)alloc(512 * 4);
    int*   count   = (int*)alloc((size_t)N_NODES * 4);
    int*   offsets = (int*)alloc((size_t)(N_NODES + 1) * 4);
    int*   cursor  = (int*)alloc((size_t)N_NODES * 4);
    int2*  sep     = (int2*)alloc((size_t)N_EDGES * 8);
    int*   tileSum = (int*)alloc((size_t)SCAN_TILES * 4);
    unsigned short* Bpack = (unsigned short*)alloc((size_t)2 * 131072 * 2);   // 512 KB

    hipMemsetAsync(count, 0, (size_t)N_NODES * 4, stream);
    hipMemsetAsync(bn0acc, 0, 10 * 4, stream);

    // fused: BN0 stats | edge histogram | pack mu/ls weights
    prep<<<PREP_BN0 + PREP_EC + PREP_PW, 256, 0, stream>>>(
        h, bn0acc, dst, count, mu_Wl, mu_Wr, ls_Wl, ls_Wr, Bpack);

    // CSR by dst — two-level scan (wave-shfl local scan, fused tile prefix)
    local_scan<<<SCAN_TILES, 1024, 0, stream>>>(count, offsets, tileSum);
    add_prefix<<<SCAN_TILES, 1024, 0, stream>>>(offsets, tileSum, cursor);
    edge_scatter<<<(N_EDGES + 255) / 256, 256, 0, stream>>>(dst, src, ew, cursor, sep);

    // conv1 (concat) with fused BN0 finalize+apply, reg-resident weights
    gemm_k5<<<K5_BLOCKS, 128, 0, stream>>>(h, bn0acc, bn0g, bn0b,
                                           c1_Wl, c1_bl, c1_Wr, c1_br, xl, xr);
    agg_concat<<<AGG_BLOCKS, 256, 0, stream>>>(xl, xr, c1_We, c1_att, offsets,
                                               sep, c1_bias, xBh);

    // BN1 stats (atomic-free two-phase); apply+ReLU fused into gemm_mfma A-load
    bn1_reduce<<<BN1_BLOCKS, 256, 0, stream>>>(xBh, bn1part);
    bn1_finalize<<<8, 256, 0, stream>>>(bn1part, bn1g, bn1b, bn1ss);

    // mu and log_std linears: one conv per block (grid 1564), fused BN1+ReLU A-load,
    // operand-swapped MFMA -> coalesced 8B C-stores
    gemm_mfma<<<1564, 512, 0, stream>>>(xBh, bn1ss, Bpack,
                                        mu_bl, mu_br, ls_bl, ls_br,
                                        xl, xr, xl2, xr2);

    // fused dual aggregation (mu + log_std, conv-per-lane-half), persistent waves
    agg_dual<<<AGG_BLOCKS, 256, 0, stream>>>(xl, xr, xl2, xr2,
                                             mu_We, mu_att, ls_We, ls_att,
                                             offsets, sep,
                                             mu_bias, ls_bias, out_mu, out_ls);
}

// Round 8
// 426.694 us; speedup vs baseline: 1.0473x; 1.0473x over previous
//
#include <hip/hip_runtime.h>
#include <math.h>

#define N_NODES 50000
#define N_EDGES 300000
#define BN_EPS 1e-5f
#define NEG_SLOPE 0.2f

// 50000 rows pad to 3128 row-blocks of 16 (50048)
#define RB_COUNT 3128
#define SCAN_TILES 49    // 49*1024 = 50176 >= N_NODES
#define BN1_BLOCKS 523   // 523*96 = 50208 >= N_NODES
#define K5_BLOCKS 1024

// persistent aggregation grid: 8 blocks/CU x 256 CUs, 4 waves/block
#define AGG_BLOCKS 2048
#define AGG_STRIDE (AGG_BLOCKS * 4)

// prep kernel block ranges
#define PREP_BN0 128
#define PREP_EC  1172    // (300000+255)/256
#define PREP_PW  128

typedef short bf8v __attribute__((ext_vector_type(8)));
typedef float f4v __attribute__((ext_vector_type(4)));
typedef float f2v __attribute__((ext_vector_type(2)));

__device__ inline unsigned short f2bf(float f) {
    union { float f; unsigned u; } c; c.f = f;
    unsigned r = c.u + 0x7fffu + ((c.u >> 16) & 1u);
    return (unsigned short)(r >> 16);
}

__device__ inline unsigned f2bf2(float lo, float hi) {
    return (unsigned)f2bf(lo) | ((unsigned)f2bf(hi) << 16);
}

// unpack 2 bf16 (one dword) -> float2; lo -> .x, hi -> .y
__device__ inline f2v bfpair(unsigned u) {
    union { unsigned u; float f; } lo, hi;
    lo.u = u << 16;
    hi.u = u & 0xffff0000u;
    f2v r; r.x = lo.f; r.y = hi.f;
    return r;
}

// async global->LDS DMA, 16B per lane; LDS dest = ldsbase + lane*16 (wave-uniform base)
__device__ inline void async_copy16(void* lds, const void* g) {
    __builtin_amdgcn_global_load_lds(
        (const __attribute__((address_space(1))) unsigned int*)g,
        (__attribute__((address_space(3))) unsigned int*)lds, 16, 0, 0);
}

// ---------------- prep: BN0 stats | edge_count | pack_w (independent, block-split) ------
__global__ __launch_bounds__(256) void prep(
        const float* __restrict__ h, float* __restrict__ acc,
        const int* __restrict__ dst, int* __restrict__ count,
        const float* __restrict__ Wl0, const float* __restrict__ Wr0,
        const float* __restrict__ Wl1, const float* __restrict__ Wr1,
        unsigned short* __restrict__ bp) {
    int b = blockIdx.x;
    if (b < PREP_BN0) {
        // ---- BN0 column stats ----
        __shared__ float lds[4][10];
        int tid = threadIdx.x;
        int lane = tid & 63, wave = tid >> 6;
        float ls[5] = {0,0,0,0,0}, lq[5] = {0,0,0,0,0};
        for (int r = b * 256 + tid; r < N_NODES; r += PREP_BN0 * 256) {
            #pragma unroll
            for (int k = 0; k < 5; k++) {
                float v = h[r*5 + k];
                ls[k] += v; lq[k] += v*v;
            }
        }
        #pragma unroll
        for (int k = 0; k < 5; k++) {
            #pragma unroll
            for (int m = 1; m <= 32; m <<= 1) {
                ls[k] += __shfl_xor(ls[k], m, 64);
                lq[k] += __shfl_xor(lq[k], m, 64);
            }
        }
        if (lane == 0) {
            #pragma unroll
            for (int k = 0; k < 5; k++) { lds[wave][k] = ls[k]; lds[wave][5+k] = lq[k]; }
        }
        __syncthreads();
        if (tid < 10) {
            float s = lds[0][tid] + lds[1][tid] + lds[2][tid] + lds[3][tid];
            atomicAdd(&acc[tid], s);
        }
    } else if (b < PREP_BN0 + PREP_EC) {
        // ---- edge histogram by dst ----
        int e = (b - PREP_BN0) * 256 + threadIdx.x;
        if (e < N_EDGES) atomicAdd(&count[dst[e]], 1);
    } else {
        // ---- pack mu/ls weights -> bf16 MFMA B-fragment order ----
        int t = (b - PREP_BN0 - PREP_EC) * 256 + threadIdx.x;   // 32768 threads exact
        int lane = t & 63;
        int nt = (t >> 6) & 31;
        int kc = (t >> 11) & 7;
        int conv = t >> 14;
        int col = nt * 16 + (lane & 15);
        int k0 = kc * 32 + (lane >> 4) * 8;
        const float* W = conv ? (col < 256 ? Wl1 : Wr1) : (col < 256 ? Wl0 : Wr0);
        int c = col & 255;
        union { unsigned short h[8]; uint4 u; } tmp;
        #pragma unroll
        for (int j = 0; j < 8; j++) tmp.h[j] = f2bf(W[(size_t)(k0 + j) * 256 + c]);
        *reinterpret_cast<uint4*>(bp + (size_t)t * 8) = tmp.u;
    }
}

// ---------------- CSR scan: wave-shfl local scan (2 barriers) ----------------
__global__ void local_scan(const int* __restrict__ count, int* __restrict__ offsets,
                           int* __restrict__ tileSum) {
    __shared__ int wsum[16];
    int tid = threadIdx.x;
    int lane = tid & 63, wv = tid >> 6;
    int i = blockIdx.x * 1024 + tid;
    int v = (i < N_NODES) ? count[i] : 0;
    int inc = v;
    #pragma unroll
    for (int off = 1; off < 64; off <<= 1) {
        int t = __shfl_up(inc, off, 64);
        if (lane >= off) inc += t;
    }
    if (lane == 63) wsum[wv] = inc;
    __syncthreads();
    if (wv == 0) {
        int val = (lane < 16) ? wsum[lane] : 0;
        int inc2 = val;
        #pragma unroll
        for (int off = 1; off < 16; off <<= 1) {
            int t = __shfl_up(inc2, off, 64);
            if (lane >= off) inc2 += t;
        }
        if (lane < 16) wsum[lane] = inc2 - val;   // exclusive wave prefix
    }
    __syncthreads();
    int excl = inc - v + wsum[wv];
    if (i < N_NODES) offsets[i] = excl;           // local exclusive
    if (tid == 1023) tileSum[blockIdx.x] = excl + v;
}

// add_prefix with fused tile-prefix computation (each block wave-reduces its prefix)
__global__ void add_prefix(int* __restrict__ offsets, const int* __restrict__ tileSum,
                           int* __restrict__ cursor) {
    __shared__ int spref;
    int tid = threadIdx.x;
    if (tid < 64) {
        int v = (tid < blockIdx.x) ? tileSum[tid] : 0;   // blockIdx.x <= 48 < 64
        #pragma unroll
        for (int m = 1; m <= 32; m <<= 1) v += __shfl_xor(v, m, 64);
        if (tid == 0) spref = v;
    }
    __syncthreads();
    int i = blockIdx.x * 1024 + tid;
    if (i < N_NODES) {
        int o = offsets[i] + spref;
        offsets[i] = o;
        cursor[i] = o;
    }
    if (blockIdx.x == 0 && tid == 0) offsets[N_NODES] = N_EDGES;  // total is constant
}

// scatter edges into CSR order as packed (src, edge-weight) int2
__global__ void edge_scatter(const int* __restrict__ dst, const int* __restrict__ src,
                             const float* __restrict__ ew, int* __restrict__ cursor,
                             int2* __restrict__ sep) {
    int e = blockIdx.x * blockDim.x + threadIdx.x;
    if (e < N_EDGES) {
        int pos = atomicAdd(&cursor[dst[e]], 1);
        sep[pos] = make_int2(src[e], __float_as_int(ew[e]));
    }
}

// ---------------- conv1 linear (K=5), fused BN0 finalize+apply, reg-resident weights ----
__global__ __launch_bounds__(128) void gemm_k5(const float* __restrict__ h,
        const float* __restrict__ acc10, const float* __restrict__ g5,
        const float* __restrict__ b5,
        const float* __restrict__ Wl, const float* __restrict__ bl,
        const float* __restrict__ Wr, const float* __restrict__ br,
        unsigned short* __restrict__ xl, unsigned short* __restrict__ xr) {
    int c = threadIdx.x * 2;
    float sc[5], sh[5];
    #pragma unroll
    for (int k = 0; k < 5; k++) {
        float mean = acc10[k] * (1.f / N_NODES);
        float var  = acc10[5 + k] * (1.f / N_NODES) - mean * mean;
        float s = g5[k] * rsqrtf(var + BN_EPS);
        sc[k] = s; sh[k] = b5[k] - mean * s;
    }
    float wl0[5], wl1[5], wr0[5], wr1[5];
    #pragma unroll
    for (int k = 0; k < 5; k++) {
        wl0[k] = Wl[k*256 + c]; wl1[k] = Wl[k*256 + c + 1];
        wr0[k] = Wr[k*256 + c]; wr1[k] = Wr[k*256 + c + 1];
    }
    float bl0 = bl[c], bl1 = bl[c+1], br0 = br[c], br1 = br[c+1];
    int n = blockIdx.x;
    float hv[5];
    if (n < N_NODES) {
        #pragma unroll
        for (int k = 0; k < 5; k++) hv[k] = h[n*5 + k];
    }
    for (; n < N_NODES; n += K5_BLOCKS) {
        int n2 = n + K5_BLOCKS;
        float hn[5] = {0,0,0,0,0};
        if (n2 < N_NODES) {
            #pragma unroll
            for (int k = 0; k < 5; k++) hn[k] = h[n2*5 + k];
        }
        float l0 = bl0, l1 = bl1, r0 = br0, r1 = br1;
        #pragma unroll
        for (int k = 0; k < 5; k++) {
            float a = hv[k] * sc[k] + sh[k];
            l0 += a * wl0[k]; l1 += a * wl1[k];
            r0 += a * wr0[k]; r1 += a * wr1[k];
        }
        *reinterpret_cast<unsigned*>(xl + (size_t)n*256 + c) = f2bf2(l0, l1);
        *reinterpret_cast<unsigned*>(xr + (size_t)n*256 + c) = f2bf2(r0, r1);
        #pragma unroll
        for (int k = 0; k < 5; k++) hv[k] = hn[k];
    }
}

// ---------------- big linear via MFMA: BN1+ReLU fused A-load, ONE conv per block --------
// grid 1564: blocks [0,782) -> conv A (mu), [782,1564) -> conv B (ls).
// OPERAND-SWAPPED MFMA: acc holds C^T fragments -> each lane owns node row (lane&15)
// and 4 CONSECUTIVE output cols (reg 0..3) -> packed 8B C-stores (16 instead of 64x2B).
__global__ __launch_bounds__(512, 4) void gemm_mfma(const unsigned short* __restrict__ xh,
        const float* __restrict__ ss1,
        const unsigned short* __restrict__ bp,
        const float* __restrict__ bl0, const float* __restrict__ br0,
        const float* __restrict__ bl1, const float* __restrict__ br1,
        unsigned short* __restrict__ xlA, unsigned short* __restrict__ xrA,
        unsigned short* __restrict__ xlB, unsigned short* __restrict__ xrB) {
    __shared__ unsigned short Bs[2][32][512];   // [buf][frag f=h*16+t][lane*8]
    int cv = blockIdx.x >= 782;
    int bb = cv ? blockIdx.x - 782 : blockIdx.x;
    int lane = threadIdx.x & 63;
    int wave = threadIdx.x >> 6;
    int h = wave & 1;
    int rb = bb * 4 + (wave >> 1);

    const unsigned short* bsrc = bp + (size_t)cv * 131072 + lane * 8;
    auto stage = [&](int buf, int kc) {
        #pragma unroll
        for (int j = 0; j < 4; j++) {
            int f = wave * 4 + j;
            async_copy16(&Bs[buf][f][lane * 8], bsrc + (size_t)kc * 16384 + f * 512);
        }
    };
    stage(0, 0);

    // ---- load A fragments from xBh with fused BN1 scale/shift + ReLU -> bf16 ----
    int row = rb * 16 + (lane & 15);
    int k0b = (lane >> 4) * 8;
    bool rok = row < N_NODES;
    bf8v a[8];
    #pragma unroll
    for (int kc = 0; kc < 8; kc++) {
        int k0 = kc * 32 + k0b;
        union { unsigned short hh[8]; uint4 u; bf8v v; } tmp;
        if (rok) {
            uint4 u = *(const uint4*)(xh + (size_t)row * 256 + k0);
            f4v s0 = *(const f4v*)(ss1 + k0);
            f4v s1 = *(const f4v*)(ss1 + k0 + 4);
            f4v h0 = *(const f4v*)(ss1 + 256 + k0);
            f4v h1 = *(const f4v*)(ss1 + 256 + k0 + 4);
            float f[8];
            f2v p;
            p = bfpair(u.x); f[0] = p.x; f[1] = p.y;
            p = bfpair(u.y); f[2] = p.x; f[3] = p.y;
            p = bfpair(u.z); f[4] = p.x; f[5] = p.y;
            p = bfpair(u.w); f[6] = p.x; f[7] = p.y;
            float scv[8] = {s0.x, s0.y, s0.z, s0.w, s1.x, s1.y, s1.z, s1.w};
            float shv[8] = {h0.x, h0.y, h0.z, h0.w, h1.x, h1.y, h1.z, h1.w};
            #pragma unroll
            for (int j = 0; j < 8; j++) {
                float v = f[j] * scv[j] + shv[j];
                v = v > 0.f ? v : 0.f;
                tmp.hh[j] = f2bf(v);
            }
        } else {
            tmp.u = (uint4){0u, 0u, 0u, 0u};
        }
        a[kc] = tmp.v;
    }

    f4v acc[16];
    #pragma unroll
    for (int t = 0; t < 16; t++) acc[t] = (f4v){0.f, 0.f, 0.f, 0.f};

    for (int kc = 0; kc < 8; kc++) {
        __syncthreads();                 // staging of buf kc&1 done; prev buf free
        if (kc < 7) stage((kc + 1) & 1, kc + 1);
        const unsigned short* bb2 = &Bs[kc & 1][h * 16][lane * 8];
        #pragma unroll
        for (int t = 0; t < 16; t++) {
            bf8v b = *reinterpret_cast<const bf8v*>(bb2 + t * 512);
            // swapped operands: acc[t] = C^T fragment
            acc[t] = __builtin_amdgcn_mfma_f32_16x16x32_bf16(b, a[kc], acc[t], 0, 0, 0);
        }
    }

    // ---- C^T epilogue: lane owns node row (lane&15), cols q*4..q*4+3 within each t ----
    int q = lane >> 4;
    unsigned short* outp = cv ? (h ? xrB : xlB) : (h ? xrA : xlA);
    const float* bias = cv ? (h ? br1 : bl1) : (h ? br0 : bl0);
    if (rok) {
        unsigned short* orow = outp + (size_t)row * 256 + q * 4;
        #pragma unroll
        for (int t = 0; t < 16; t++) {
            f4v bv = *(const f4v*)(bias + t * 16 + q * 4);
            uint2 u;
            u.x = f2bf2(acc[t][0] + bv.x, acc[t][1] + bv.y);
            u.y = f2bf2(acc[t][2] + bv.z, acc[t][3] + bv.w);
            *reinterpret_cast<uint2*>(orow + t * 16) = u;
        }
    }
}

// ---------------- fused GATv2 edge phase (concat conv1), persistent waves ----------
// 2048 blocks x 4 waves; each wave grid-strides nodes (stride 8192). Per node:
// TWO edge streams (lanes 0-31 even, 32-63 odd), NO-MAX softmax, 2-deep pipeline.
// Bias loaded at write time (keeps held registers low).
__global__ __launch_bounds__(256) void agg_concat(
        const unsigned short* __restrict__ xl, const unsigned short* __restrict__ xr,
        const float* __restrict__ We, const float* __restrict__ att,
        const int* __restrict__ offsets, const int2* __restrict__ sep,
        const float* __restrict__ bias,
        unsigned short* __restrict__ outh) {
    int gw = blockIdx.x * 4 + (threadIdx.x >> 6);
    int lane = threadIdx.x & 63;
    int half = lane >> 5;
    int sub  = lane & 31;
    int cb   = (sub >> 4) * 128 + (sub & 15) * 8;
    f2v wv[4], av[4];
    {
        f4v t0 = *(const f4v*)(We + cb);
        f4v t1 = *(const f4v*)(We + cb + 4);
        wv[0] = (f2v){t0.x, t0.y}; wv[1] = (f2v){t0.z, t0.w};
        wv[2] = (f2v){t1.x, t1.y}; wv[3] = (f2v){t1.z, t1.w};
        t0 = *(const f4v*)(att + cb);
        t1 = *(const f4v*)(att + cb + 4);
        av[0] = (f2v){t0.x, t0.y}; av[1] = (f2v){t0.z, t0.w};
        av[2] = (f2v){t1.x, t1.y}; av[3] = (f2v){t1.z, t1.w};
    }
    int n = gw;
    int beg = 0, end = 0;
    if (n < N_NODES) { beg = offsets[n]; end = offsets[n + 1]; }
    while (n < N_NODES) {
        int nn = n + AGG_STRIDE;
        int nbeg = 0, nend = 0;
        if (nn < N_NODES) { nbeg = offsets[nn]; nend = offsets[nn + 1]; }  // prefetch
        uint4 r8 = *(const uint4*)(xr + ((size_t)n << 8) + cb);
        f2v rv[4];
        rv[0] = bfpair(r8.x); rv[1] = bfpair(r8.y);
        rv[2] = bfpair(r8.z); rv[3] = bfpair(r8.w);

        float den = 0.f;
        f2v acc[4];
        #pragma unroll
        for (int j = 0; j < 4; j++) acc[j] = (f2v){0.f, 0.f};

        int i = beg + half;
        float wN = 0.f;
        int2 seP = make_int2(0, 0);
        uint4 lN = {0u, 0u, 0u, 0u};
        if (i < end) {
            int2 se = sep[i];
            wN = __int_as_float(se.y);
            lN = *(const uint4*)(xl + ((size_t)se.x << 8) + cb);
        }
        if (i + 2 < end) seP = sep[i + 2];
        for (; i < end; i += 2) {
            uint4 l8 = lN; float w = wN;
            if (i + 2 < end) {                           // gather uses pre-fetched index
                lN = *(const uint4*)(xl + ((size_t)seP.x << 8) + cb);
                wN = __int_as_float(seP.y);
            }
            if (i + 4 < end) seP = sep[i + 4];
            f2v w2 = (f2v){w, w};
            f2v lv[4];
            lv[0] = bfpair(l8.x); lv[1] = bfpair(l8.y);
            lv[2] = bfpair(l8.z); lv[3] = bfpair(l8.w);
            f2v da = (f2v){0.f, 0.f};
            #pragma unroll
            for (int j = 0; j < 4; j++) {
                f2v v = lv[j] + rv[j] + w2 * wv[j];
                f2v s = v * (f2v){NEG_SLOPE, NEG_SLOPE};
                v.x = fmaxf(v.x, s.x); v.y = fmaxf(v.y, s.y);   // leaky relu
                da += v * av[j];
            }
            float a = da.x + da.y;
            a += __shfl_xor(a, 1, 64);
            a += __shfl_xor(a, 2, 64);
            a += __shfl_xor(a, 4, 64);
            a += __shfl_xor(a, 8, 64);                   // per-head alpha (16-lane groups)
            float p = __expf(a);
            den += p;
            f2v p2 = (f2v){p, p};
            #pragma unroll
            for (int j = 0; j < 4; j++) acc[j] += p2 * lv[j];
        }
        // merge even/odd streams (pure adds)
        den += __shfl_xor(den, 32, 64);
        #pragma unroll
        for (int j = 0; j < 4; j++) {
            f2v ao;
            ao.x = __shfl_xor(acc[j].x, 32, 64);
            ao.y = __shfl_xor(acc[j].y, 32, 64);
            acc[j] += ao;
        }
        float inv = 1.f / (den + 1e-16f);
        if (lane < 32) {
            f4v b0 = *(const f4v*)(bias + cb);
            f4v b1 = *(const f4v*)(bias + cb + 4);
            union { unsigned short hh[8]; uint4 u; } o;
            o.hh[0] = f2bf(acc[0].x * inv + b0.x);
            o.hh[1] = f2bf(acc[0].y * inv + b0.y);
            o.hh[2] = f2bf(acc[1].x * inv + b0.z);
            o.hh[3] = f2bf(acc[1].y * inv + b0.w);
            o.hh[4] = f2bf(acc[2].x * inv + b1.x);
            o.hh[5] = f2bf(acc[2].y * inv + b1.y);
            o.hh[6] = f2bf(acc[3].x * inv + b1.z);
            o.hh[7] = f2bf(acc[3].y * inv + b1.w);
            *(uint4*)(outh + (size_t)n * 256 + cb) = o.u;
        }
        n = nn; beg = nbeg; end = nend;
    }
}

// ---------------- fused DUAL GATv2 edge phase (mu + log_std), persistent waves ----------
// R5 structure (two edge streams, both convs per lane, NO-MAX softmax). Bias loaded
// at write time instead of preamble (-8 held VGPRs, targeting the 64-reg wave-slot
// boundary). NO forced occupancy bound (R6's (256,8) caused catastrophic spills).
__global__ __launch_bounds__(256) void agg_dual(
        const unsigned short* __restrict__ xlA, const unsigned short* __restrict__ xrA,
        const unsigned short* __restrict__ xlB, const unsigned short* __restrict__ xrB,
        const float* __restrict__ WeA, const float* __restrict__ attA,
        const float* __restrict__ WeB, const float* __restrict__ attB,
        const int* __restrict__ offsets, const int2* __restrict__ sep,
        const float* __restrict__ biasA, const float* __restrict__ biasB,
        float* __restrict__ outA, float* __restrict__ outB) {
    int gw = blockIdx.x * 4 + (threadIdx.x >> 6);
    int lane = threadIdx.x & 63;
    int half = lane >> 5;
    int sub  = lane & 31;
    int cb   = (sub >> 4) * 128 + (sub & 15) * 8;
    int c0 = (lane & 15) * 8;
    f2v wvA[4], avA[4], wvB[4], avB[4];
    {
        f4v t0 = *(const f4v*)(WeA + cb);
        f4v t1 = *(const f4v*)(WeA + cb + 4);
        wvA[0] = (f2v){t0.x, t0.y}; wvA[1] = (f2v){t0.z, t0.w};
        wvA[2] = (f2v){t1.x, t1.y}; wvA[3] = (f2v){t1.z, t1.w};
        t0 = *(const f4v*)(attA + cb);
        t1 = *(const f4v*)(attA + cb + 4);
        avA[0] = (f2v){t0.x, t0.y}; avA[1] = (f2v){t0.z, t0.w};
        avA[2] = (f2v){t1.x, t1.y}; avA[3] = (f2v){t1.z, t1.w};
        t0 = *(const f4v*)(WeB + cb);
        t1 = *(const f4v*)(WeB + cb + 4);
        wvB[0] = (f2v){t0.x, t0.y}; wvB[1] = (f2v){t0.z, t0.w};
        wvB[2] = (f2v){t1.x, t1.y}; wvB[3] = (f2v){t1.z, t1.w};
        t0 = *(const f4v*)(attB + cb);
        t1 = *(const f4v*)(attB + cb + 4);
        avB[0] = (f2v){t0.x, t0.y}; avB[1] = (f2v){t0.z, t0.w};
        avB[2] = (f2v){t1.x, t1.y}; avB[3] = (f2v){t1.z, t1.w};
    }
    int n = gw;
    int beg = 0, end = 0;
    if (n < N_NODES) { beg = offsets[n]; end = offsets[n + 1]; }
    while (n < N_NODES) {
        int nn = n + AGG_STRIDE;
        int nbeg = 0, nend = 0;
        if (nn < N_NODES) { nbeg = offsets[nn]; nend = offsets[nn + 1]; }  // prefetch
        uint4 r8A = *(const uint4*)(xrA + ((size_t)n << 8) + cb);
        uint4 r8B = *(const uint4*)(xrB + ((size_t)n << 8) + cb);
        f2v rvA[4], rvB[4];
        rvA[0] = bfpair(r8A.x); rvA[1] = bfpair(r8A.y);
        rvA[2] = bfpair(r8A.z); rvA[3] = bfpair(r8A.w);
        rvB[0] = bfpair(r8B.x); rvB[1] = bfpair(r8B.y);
        rvB[2] = bfpair(r8B.z); rvB[3] = bfpair(r8B.w);

        float dA = 0.f, dB = 0.f;
        f2v accA[4], accB[4];
        #pragma unroll
        for (int j = 0; j < 4; j++) { accA[j] = (f2v){0.f, 0.f}; accB[j] = (f2v){0.f, 0.f}; }

        int i = beg + half;
        float wN = 0.f;
        int2 seP = make_int2(0, 0);
        uint4 lNA = {0u, 0u, 0u, 0u}, lNB = {0u, 0u, 0u, 0u};
        if (i < end) {
            int2 se = sep[i];
            wN = __int_as_float(se.y);
            size_t o = ((size_t)se.x << 8) + cb;
            lNA = *(const uint4*)(xlA + o);
            lNB = *(const uint4*)(xlB + o);
        }
        if (i + 2 < end) seP = sep[i + 2];
        for (; i < end; i += 2) {
            uint4 lA = lNA, lB = lNB; float w = wN;
            if (i + 2 < end) {                           // gathers use pre-fetched index
                size_t o = ((size_t)seP.x << 8) + cb;
                lNA = *(const uint4*)(xlA + o);
                lNB = *(const uint4*)(xlB + o);
                wN = __int_as_float(seP.y);
            }
            if (i + 4 < end) seP = sep[i + 4];
            f2v w2 = (f2v){w, w};
            f2v lvA[4], lvB[4];
            lvA[0] = bfpair(lA.x); lvA[1] = bfpair(lA.y);
            lvA[2] = bfpair(lA.z); lvA[3] = bfpair(lA.w);
            lvB[0] = bfpair(lB.x); lvB[1] = bfpair(lB.y);
            lvB[2] = bfpair(lB.z); lvB[3] = bfpair(lB.w);
            f2v daA = (f2v){0.f, 0.f}, daB = (f2v){0.f, 0.f};
            #pragma unroll
            for (int j = 0; j < 4; j++) {
                f2v vA = lvA[j] + rvA[j] + w2 * wvA[j];
                f2v sA = vA * (f2v){NEG_SLOPE, NEG_SLOPE};
                vA.x = fmaxf(vA.x, sA.x); vA.y = fmaxf(vA.y, sA.y);
                daA += vA * avA[j];
                f2v vB = lvB[j] + rvB[j] + w2 * wvB[j];
                f2v sB = vB * (f2v){NEG_SLOPE, NEG_SLOPE};
                vB.x = fmaxf(vB.x, sB.x); vB.y = fmaxf(vB.y, sB.y);
                daB += vB * avB[j];
            }
            float aA = daA.x + daA.y, aB = daB.x + daB.y;
            float tA, tB;
            tA = __shfl_xor(aA, 1, 64); tB = __shfl_xor(aB, 1, 64); aA += tA; aB += tB;
            tA = __shfl_xor(aA, 2, 64); tB = __shfl_xor(aB, 2, 64); aA += tA; aB += tB;
            tA = __shfl_xor(aA, 4, 64); tB = __shfl_xor(aB, 4, 64); aA += tA; aB += tB;
            tA = __shfl_xor(aA, 8, 64); tB = __shfl_xor(aB, 8, 64); aA += tA; aB += tB;
            float pA = __expf(aA), pB = __expf(aB);
            dA += pA; dB += pB;
            f2v pA2 = (f2v){pA, pA}, pB2 = (f2v){pB, pB};
            #pragma unroll
            for (int j = 0; j < 4; j++) {
                accA[j] += pA2 * lvA[j];
                accB[j] += pB2 * lvB[j];
            }
        }
        // merge even/odd streams (pure adds)
        dA += __shfl_xor(dA, 32, 64);
        dB += __shfl_xor(dB, 32, 64);
        #pragma unroll
        for (int j = 0; j < 4; j++) {
            f2v ao;
            ao.x = __shfl_xor(accA[j].x, 32, 64);
            ao.y = __shfl_xor(accA[j].y, 32, 64);
            accA[j] += ao;
            ao.x = __shfl_xor(accB[j].x, 32, 64);
            ao.y = __shfl_xor(accB[j].y, 32, 64);
            accB[j] += ao;
        }
        float invA = 1.f / (dA + 1e-16f);
        float invB = 1.f / (dB + 1e-16f);
        float oA[8], oB[8], poA[8], poB[8];
        #pragma unroll
        for (int j = 0; j < 4; j++) {
            oA[2*j]   = accA[j].x * invA;
            oA[2*j+1] = accA[j].y * invA;
            oB[2*j]   = accB[j].x * invB;
            oB[2*j+1] = accB[j].y * invB;
        }
        #pragma unroll
        for (int j = 0; j < 8; j++) {
            poA[j] = __shfl_xor(oA[j], 16, 64);   // other head, same channels
            poB[j] = __shfl_xor(oB[j], 16, 64);
        }
        int q = lane >> 4;
        if (q == 0) {                              // lanes 0-15 write conv A (mu)
            f4v b0 = *(const f4v*)(biasA + c0);
            f4v b1 = *(const f4v*)(biasA + c0 + 4);
            float r[8];
            r[0] = (oA[0]+poA[0])*0.5f + b0.x; r[1] = (oA[1]+poA[1])*0.5f + b0.y;
            r[2] = (oA[2]+poA[2])*0.5f + b0.z; r[3] = (oA[3]+poA[3])*0.5f + b0.w;
            r[4] = (oA[4]+poA[4])*0.5f + b1.x; r[5] = (oA[5]+poA[5])*0.5f + b1.y;
            r[6] = (oA[6]+poA[6])*0.5f + b1.z; r[7] = (oA[7]+poA[7])*0.5f + b1.w;
            *(float4*)(outA + (size_t)n * 128 + c0)     = *(float4*)&r[0];
            *(float4*)(outA + (size_t)n * 128 + c0 + 4) = *(float4*)&r[4];
        } else if (q == 2) {                       // lanes 32-47 write conv B (log_std)
            f4v b0 = *(const f4v*)(biasB + c0);
            f4v b1 = *(const f4v*)(biasB + c0 + 4);
            float r[8];
            r[0] = (oB[0]+poB[0])*0.5f + b0.x; r[1] = (oB[1]+poB[1])*0.5f + b0.y;
            r[2] = (oB[2]+poB[2])*0.5f + b0.z; r[3] = (oB[3]+poB[3])*0.5f + b0.w;
            r[4] = (oB[4]+poB[4])*0.5f + b1.x; r[5] = (oB[5]+poB[5])*0.5f + b1.y;
            r[6] = (oB[6]+poB[6])*0.5f + b1.z; r[7] = (oB[7]+poB[7])*0.5f + b1.w;
            *(float4*)(outB + (size_t)n * 128 + c0)     = *(float4*)&r[0];
            *(float4*)(outB + (size_t)n * 128 + c0 + 4) = *(float4*)&r[4];
        }
        n = nn; beg = nbeg; end = nend;
    }
}

// ---------------- BN1 stats, phase 1: per-block partials (bf16 input, NO atomics) --------
__global__ void bn1_reduce(const unsigned short* __restrict__ xh, float* __restrict__ part) {
    __shared__ float lds[256][9];   // stride 9 floats -> no bank conflicts
    int tid = threadIdx.x;
    int cg = tid & 63;              // col group: cols cg*4 .. cg*4+3
    int ph = tid >> 6;              // row phase 0..3
    int r0 = blockIdx.x * 96;
    float s[4] = {0,0,0,0}, q[4] = {0,0,0,0};
    #pragma unroll
    for (int it = 0; it < 24; it++) {
        int row = r0 + it * 4 + ph;
        if (row < N_NODES) {
            uint2 v = *(const uint2*)(xh + (size_t)row * 256 + cg * 4);
            f2v p0 = bfpair(v.x), p1 = bfpair(v.y);
            s[0] += p0.x; s[1] += p0.y; s[2] += p1.x; s[3] += p1.y;
            q[0] += p0.x*p0.x; q[1] += p0.y*p0.y; q[2] += p1.x*p1.x; q[3] += p1.y*p1.y;
        }
    }
    #pragma unroll
    for (int j = 0; j < 4; j++) { lds[tid][j] = s[j]; lds[tid][4+j] = q[j]; }
    __syncthreads();
    if (tid < 64) {
        float4 sv, qv;
        float* svp = (float*)&sv; float* qvp = (float*)&qv;
        #pragma unroll
        for (int j = 0; j < 4; j++) {
            svp[j] = lds[tid][j] + lds[tid+64][j] + lds[tid+128][j] + lds[tid+192][j];
            qvp[j] = lds[tid][4+j] + lds[tid+64][4+j] + lds[tid+128][4+j] + lds[tid+192][4+j];
        }
        *(float4*)(part + (size_t)blockIdx.x * 512 + cg * 4) = sv;
        *(float4*)(part + (size_t)blockIdx.x * 512 + 256 + cg * 4) = qv;
    }
}

__global__ void bn1_finalize(const float* __restrict__ part, const float* __restrict__ g,
                             const float* __restrict__ b, float* __restrict__ ss1) {
    __shared__ float lds[8][64];
    int t = threadIdx.x;
    int c = blockIdx.x * 32 + (t & 31);
    int ph = t >> 5;                 // 0..7
    float s = 0.f, q = 0.f;
    for (int bi = ph; bi < BN1_BLOCKS; bi += 8) {
        s += part[(size_t)bi * 512 + c];
        q += part[(size_t)bi * 512 + 256 + c];
    }
    lds[ph][t & 31] = s;
    lds[ph][32 + (t & 31)] = q;
    __syncthreads();
    if (t < 32) {
        float ss = 0.f, qq = 0.f;
        #pragma unroll
        for (int p = 0; p < 8; p++) { ss += lds[p][t]; qq += lds[p][32 + t]; }
        float mean = ss * (1.f / N_NODES);
        float var  = qq * (1.f / N_NODES) - mean * mean;
        float sc = g[c] * rsqrtf(var + BN_EPS);
        ss1[c] = sc;
        ss1[256 + c] = b[c] - mean * sc;
    }
}

extern "C" void kernel_launch(void* const* d_in, const int* in_sizes, int n_in,
                              void* d_out, int out_size, void* d_ws, size_t ws_size,
                              hipStream_t stream) {
    const float* h          = (const float*)d_in[0];
    const int*   edge_index = (const int*)d_in[1];
    const int*   src = edge_index;
    const int*   dst = edge_index + N_EDGES;
    const float* ew   = (const float*)d_in[2];
    const float* bn0g = (const float*)d_in[3];
    const float* bn0b = (const float*)d_in[4];
    const float* bn1g = (const float*)d_in[5];
    const float* bn1b = (const float*)d_in[6];
    const float* c1_Wl = (const float*)d_in[7];
    const float* c1_bl = (const float*)d_in[8];
    const float* c1_Wr = (const float*)d_in[9];
    const float* c1_br = (const float*)d_in[10];
    const float* c1_We = (const float*)d_in[11];
    const float* c1_att = (const float*)d_in[12];
    const float* c1_bias = (const float*)d_in[13];
    const float* mu_Wl = (const float*)d_in[14];
    const float* mu_bl = (const float*)d_in[15];
    const float* mu_Wr = (const float*)d_in[16];
    const float* mu_br = (const float*)d_in[17];
    const float* mu_We = (const float*)d_in[18];
    const float* mu_att = (const float*)d_in[19];
    const float* mu_bias = (const float*)d_in[20];
    const float* ls_Wl = (const float*)d_in[21];
    const float* ls_bl = (const float*)d_in[22];
    const float* ls_Wr = (const float*)d_in[23];
    const float* ls_br = (const float*)d_in[24];
    const float* ls_We = (const float*)d_in[25];
    const float* ls_att = (const float*)d_in[26];
    const float* ls_bias = (const float*)d_in[27];

    float* out_mu = (float*)d_out;
    float* out_ls = (float*)d_out + (size_t)N_NODES * 128;

    // workspace carve-up (256B aligned blocks)
    char* ws = (char*)d_ws;
    size_t off = 0;
    auto alloc = [&](size_t bytes) -> void* {
        void* p = ws + off;
        off += (bytes + 255) / 256 * 256;
        return p;
    };
    unsigned short* xl  = (unsigned short*)alloc((size_t)N_NODES * 256 * 2);
    unsigned short* xr  = (unsigned short*)alloc((size_t)N_NODES * 256 * 2);
    unsigned short* xBh = (unsigned short*)alloc((size_t)N_NODES * 256 * 2);  // bf16 conv1 out
    unsigned short* xl2 = (unsigned short*)alloc((size_t)N_NODES * 256 * 2);
    unsigned short* xr2 = (unsigned short*)alloc((size_t)N_NODES * 256 * 2);
    float* bn0acc  = (float*)alloc(10 * 4);
    float* bn1part = (float*)alloc((size_t)BN1_BLOCKS * 512 * 4);   // 1.07 MB
    float* bn1ss   = (float*)alloc(512 * 4);
    int*   count   = (int*)alloc((size_t)N_NODES * 4);
    int*   offsets = (int*)alloc((size_t)(N_NODES + 1) * 4);
    int*   cursor  = (int*)alloc((size_t)N_NODES * 4);
    int2*  sep     = (int2*)alloc((size_t)N_EDGES * 8);
    int*   tileSum = (int*)alloc((size_t)SCAN_TILES * 4);
    unsigned short* Bpack = (unsigned short*)alloc((size_t)2 * 131072 * 2);   // 512 KB

    hipMemsetAsync(count, 0, (size_t)N_NODES * 4, stream);
    hipMemsetAsync(bn0acc, 0, 10 * 4, stream);

    // fused: BN0 stats | edge histogram | pack mu/ls weights
    prep<<<PREP_BN0 + PREP_EC + PREP_PW, 256, 0, stream>>>(
        h, bn0acc, dst, count, mu_Wl, mu_Wr, ls_Wl, ls_Wr, Bpack);

    // CSR by dst — two-level scan (wave-shfl local scan, fused tile prefix)
    local_scan<<<SCAN_TILES, 1024, 0, stream>>>(count, offsets, tileSum);
    add_prefix<<<SCAN_TILES, 1024, 0, stream>>>(offsets, tileSum, cursor);
    edge_scatter<<<(N_EDGES + 255) / 256, 256, 0, stream>>>(dst, src, ew, cursor, sep);

    // conv1 (concat) with fused BN0 finalize+apply, reg-resident weights
    gemm_k5<<<K5_BLOCKS, 128, 0, stream>>>(h, bn0acc, bn0g, bn0b,
                                           c1_Wl, c1_bl, c1_Wr, c1_br, xl, xr);
    agg_concat<<<AGG_BLOCKS, 256, 0, stream>>>(xl, xr, c1_We, c1_att, offsets,
                                               sep, c1_bias, xBh);

    // BN1 stats (atomic-free two-phase); apply+ReLU fused into gemm_mfma A-load
    bn1_reduce<<<BN1_BLOCKS, 256, 0, stream>>>(xBh, bn1part);
    bn1_finalize<<<8, 256, 0, stream>>>(bn1part, bn1g, bn1b, bn1ss);

    // mu and log_std linears: one conv per block (grid 1564), fused BN1+ReLU A-load,
    // operand-swapped MFMA -> coalesced 8B C-stores
    gemm_mfma<<<1564, 512, 0, stream>>>(xBh, bn1ss, Bpack,
                                        mu_bl, mu_br, ls_bl, ls_br,
                                        xl, xr, xl2, xr2);

    // fused dual aggregation (mu + log_std share the CSR walk), persistent waves
    agg_dual<<<AGG_BLOCKS, 256, 0, stream>>>(xl, xr, xl2, xr2,
                                             mu_We, mu_att, ls_We, ls_att,
                                             offsets, sep,
                                             mu_bias, ls_bias, out_mu, out_ls);
}

// Round 9
// 412.362 us; speedup vs baseline: 1.0837x; 1.0348x over previous
//
#include <hip/hip_runtime.h>
#include <math.h>

#define N_NODES 50000
#define N_EDGES 300000
#define BN_EPS 1e-5f
#define NEG_SLOPE 0.2f

// 50000 rows pad to 3128 row-blocks of 16 (50048)
#define RB_COUNT 3128
#define SCAN_TILES 49    // 49*1024 = 50176 >= N_NODES
#define BN1_BLOCKS 523   // 523*96 = 50208 >= N_NODES
#define K5_BLOCKS 1024

// persistent aggregation grid: 8 blocks/CU x 256 CUs, 4 waves/block
#define AGG_BLOCKS 2048
#define AGG_STRIDE (AGG_BLOCKS * 4)

// prep kernel block ranges
#define PREP_BN0 128
#define PREP_EC  1172    // (300000+255)/256
#define PREP_PW  128

typedef short bf8v __attribute__((ext_vector_type(8)));
typedef float f4v __attribute__((ext_vector_type(4)));
typedef float f2v __attribute__((ext_vector_type(2)));

__device__ inline unsigned short f2bf(float f) {
    union { float f; unsigned u; } c; c.f = f;
    unsigned r = c.u + 0x7fffu + ((c.u >> 16) & 1u);
    return (unsigned short)(r >> 16);
}

__device__ inline unsigned f2bf2(float lo, float hi) {
    return (unsigned)f2bf(lo) | ((unsigned)f2bf(hi) << 16);
}

// unpack 2 bf16 (one dword) -> float2; lo -> .x, hi -> .y
__device__ inline f2v bfpair(unsigned u) {
    union { unsigned u; float f; } lo, hi;
    lo.u = u << 16;
    hi.u = u & 0xffff0000u;
    f2v r; r.x = lo.f; r.y = hi.f;
    return r;
}

// async global->LDS DMA, 16B per lane; LDS dest = ldsbase + lane*16 (wave-uniform base)
__device__ inline void async_copy16(void* lds, const void* g) {
    __builtin_amdgcn_global_load_lds(
        (const __attribute__((address_space(1))) unsigned int*)g,
        (__attribute__((address_space(3))) unsigned int*)lds, 16, 0, 0);
}

// ---------------- prep: BN0 stats | edge_count | pack_w (independent, block-split) ------
__global__ __launch_bounds__(256) void prep(
        const float* __restrict__ h, float* __restrict__ acc,
        const int* __restrict__ dst, int* __restrict__ count,
        const float* __restrict__ Wl0, const float* __restrict__ Wr0,
        const float* __restrict__ Wl1, const float* __restrict__ Wr1,
        unsigned short* __restrict__ bp) {
    int b = blockIdx.x;
    if (b < PREP_BN0) {
        // ---- BN0 column stats ----
        __shared__ float lds[4][10];
        int tid = threadIdx.x;
        int lane = tid & 63, wave = tid >> 6;
        float ls[5] = {0,0,0,0,0}, lq[5] = {0,0,0,0,0};
        for (int r = b * 256 + tid; r < N_NODES; r += PREP_BN0 * 256) {
            #pragma unroll
            for (int k = 0; k < 5; k++) {
                float v = h[r*5 + k];
                ls[k] += v; lq[k] += v*v;
            }
        }
        #pragma unroll
        for (int k = 0; k < 5; k++) {
            #pragma unroll
            for (int m = 1; m <= 32; m <<= 1) {
                ls[k] += __shfl_xor(ls[k], m, 64);
                lq[k] += __shfl_xor(lq[k], m, 64);
            }
        }
        if (lane == 0) {
            #pragma unroll
            for (int k = 0; k < 5; k++) { lds[wave][k] = ls[k]; lds[wave][5+k] = lq[k]; }
        }
        __syncthreads();
        if (tid < 10) {
            float s = lds[0][tid] + lds[1][tid] + lds[2][tid] + lds[3][tid];
            atomicAdd(&acc[tid], s);
        }
    } else if (b < PREP_BN0 + PREP_EC) {
        // ---- edge histogram by dst ----
        int e = (b - PREP_BN0) * 256 + threadIdx.x;
        if (e < N_EDGES) atomicAdd(&count[dst[e]], 1);
    } else {
        // ---- pack mu/ls weights -> bf16 MFMA B-fragment order ----
        int t = (b - PREP_BN0 - PREP_EC) * 256 + threadIdx.x;   // 32768 threads exact
        int lane = t & 63;
        int nt = (t >> 6) & 31;
        int kc = (t >> 11) & 7;
        int conv = t >> 14;
        int col = nt * 16 + (lane & 15);
        int k0 = kc * 32 + (lane >> 4) * 8;
        const float* W = conv ? (col < 256 ? Wl1 : Wr1) : (col < 256 ? Wl0 : Wr0);
        int c = col & 255;
        union { unsigned short h[8]; uint4 u; } tmp;
        #pragma unroll
        for (int j = 0; j < 8; j++) tmp.h[j] = f2bf(W[(size_t)(k0 + j) * 256 + c]);
        *reinterpret_cast<uint4*>(bp + (size_t)t * 8) = tmp.u;
    }
}

// ---------------- CSR scan: wave-shfl local scan (2 barriers) ----------------
__global__ void local_scan(const int* __restrict__ count, int* __restrict__ offsets,
                           int* __restrict__ tileSum) {
    __shared__ int wsum[16];
    int tid = threadIdx.x;
    int lane = tid & 63, wv = tid >> 6;
    int i = blockIdx.x * 1024 + tid;
    int v = (i < N_NODES) ? count[i] : 0;
    int inc = v;
    #pragma unroll
    for (int off = 1; off < 64; off <<= 1) {
        int t = __shfl_up(inc, off, 64);
        if (lane >= off) inc += t;
    }
    if (lane == 63) wsum[wv] = inc;
    __syncthreads();
    if (wv == 0) {
        int val = (lane < 16) ? wsum[lane] : 0;
        int inc2 = val;
        #pragma unroll
        for (int off = 1; off < 16; off <<= 1) {
            int t = __shfl_up(inc2, off, 64);
            if (lane >= off) inc2 += t;
        }
        if (lane < 16) wsum[lane] = inc2 - val;   // exclusive wave prefix
    }
    __syncthreads();
    int excl = inc - v + wsum[wv];
    if (i < N_NODES) offsets[i] = excl;           // local exclusive
    if (tid == 1023) tileSum[blockIdx.x] = excl + v;
}

// add_prefix with fused tile-prefix computation (each block wave-reduces its prefix)
__global__ void add_prefix(int* __restrict__ offsets, const int* __restrict__ tileSum,
                           int* __restrict__ cursor) {
    __shared__ int spref;
    int tid = threadIdx.x;
    if (tid < 64) {
        int v = (tid < blockIdx.x) ? tileSum[tid] : 0;   // blockIdx.x <= 48 < 64
        #pragma unroll
        for (int m = 1; m <= 32; m <<= 1) v += __shfl_xor(v, m, 64);
        if (tid == 0) spref = v;
    }
    __syncthreads();
    int i = blockIdx.x * 1024 + tid;
    if (i < N_NODES) {
        int o = offsets[i] + spref;
        offsets[i] = o;
        cursor[i] = o;
    }
    if (blockIdx.x == 0 && tid == 0) offsets[N_NODES] = N_EDGES;  // total is constant
}

// scatter edges into CSR order as packed (src, edge-weight) int2
__global__ void edge_scatter(const int* __restrict__ dst, const int* __restrict__ src,
                             const float* __restrict__ ew, int* __restrict__ cursor,
                             int2* __restrict__ sep) {
    int e = blockIdx.x * blockDim.x + threadIdx.x;
    if (e < N_EDGES) {
        int pos = atomicAdd(&cursor[dst[e]], 1);
        sep[pos] = make_int2(src[e], __float_as_int(ew[e]));
    }
}

// ---------------- conv1 linear (K=5), fused BN0 finalize+apply, reg-resident weights ----
__global__ __launch_bounds__(128) void gemm_k5(const float* __restrict__ h,
        const float* __restrict__ acc10, const float* __restrict__ g5,
        const float* __restrict__ b5,
        const float* __restrict__ Wl, const float* __restrict__ bl,
        const float* __restrict__ Wr, const float* __restrict__ br,
        unsigned short* __restrict__ xl, unsigned short* __restrict__ xr) {
    int c = threadIdx.x * 2;
    float sc[5], sh[5];
    #pragma unroll
    for (int k = 0; k < 5; k++) {
        float mean = acc10[k] * (1.f / N_NODES);
        float var  = acc10[5 + k] * (1.f / N_NODES) - mean * mean;
        float s = g5[k] * rsqrtf(var + BN_EPS);
        sc[k] = s; sh[k] = b5[k] - mean * s;
    }
    float wl0[5], wl1[5], wr0[5], wr1[5];
    #pragma unroll
    for (int k = 0; k < 5; k++) {
        wl0[k] = Wl[k*256 + c]; wl1[k] = Wl[k*256 + c + 1];
        wr0[k] = Wr[k*256 + c]; wr1[k] = Wr[k*256 + c + 1];
    }
    float bl0 = bl[c], bl1 = bl[c+1], br0 = br[c], br1 = br[c+1];
    int n = blockIdx.x;
    float hv[5];
    if (n < N_NODES) {
        #pragma unroll
        for (int k = 0; k < 5; k++) hv[k] = h[n*5 + k];
    }
    for (; n < N_NODES; n += K5_BLOCKS) {
        int n2 = n + K5_BLOCKS;
        float hn[5] = {0,0,0,0,0};
        if (n2 < N_NODES) {
            #pragma unroll
            for (int k = 0; k < 5; k++) hn[k] = h[n2*5 + k];
        }
        float l0 = bl0, l1 = bl1, r0 = br0, r1 = br1;
        #pragma unroll
        for (int k = 0; k < 5; k++) {
            float a = hv[k] * sc[k] + sh[k];
            l0 += a * wl0[k]; l1 += a * wl1[k];
            r0 += a * wr0[k]; r1 += a * wr1[k];
        }
        *reinterpret_cast<unsigned*>(xl + (size_t)n*256 + c) = f2bf2(l0, l1);
        *reinterpret_cast<unsigned*>(xr + (size_t)n*256 + c) = f2bf2(r0, r1);
        #pragma unroll
        for (int k = 0; k < 5; k++) hv[k] = hn[k];
    }
}

// ---------------- big linear via MFMA: BN1+ReLU fused A-load, ONE conv per block --------
// grid 1564: blocks [0,782) -> conv A (mu), [782,1564) -> conv B (ls).
// OPERAND-SWAPPED MFMA: acc holds C^T fragments -> each lane owns node row (lane&15)
// and 4 CONSECUTIVE output cols (reg 0..3) -> packed 8B C-stores (16 instead of 64x2B).
__global__ __launch_bounds__(512, 4) void gemm_mfma(const unsigned short* __restrict__ xh,
        const float* __restrict__ ss1,
        const unsigned short* __restrict__ bp,
        const float* __restrict__ bl0, const float* __restrict__ br0,
        const float* __restrict__ bl1, const float* __restrict__ br1,
        unsigned short* __restrict__ xlA, unsigned short* __restrict__ xrA,
        unsigned short* __restrict__ xlB, unsigned short* __restrict__ xrB) {
    __shared__ unsigned short Bs[2][32][512];   // [buf][frag f=h*16+t][lane*8]
    int cv = blockIdx.x >= 782;
    int bb = cv ? blockIdx.x - 782 : blockIdx.x;
    int lane = threadIdx.x & 63;
    int wave = threadIdx.x >> 6;
    int h = wave & 1;
    int rb = bb * 4 + (wave >> 1);

    const unsigned short* bsrc = bp + (size_t)cv * 131072 + lane * 8;
    auto stage = [&](int buf, int kc) {
        #pragma unroll
        for (int j = 0; j < 4; j++) {
            int f = wave * 4 + j;
            async_copy16(&Bs[buf][f][lane * 8], bsrc + (size_t)kc * 16384 + f * 512);
        }
    };
    stage(0, 0);

    // ---- load A fragments from xBh with fused BN1 scale/shift + ReLU -> bf16 ----
    int row = rb * 16 + (lane & 15);
    int k0b = (lane >> 4) * 8;
    bool rok = row < N_NODES;
    bf8v a[8];
    #pragma unroll
    for (int kc = 0; kc < 8; kc++) {
        int k0 = kc * 32 + k0b;
        union { unsigned short hh[8]; uint4 u; bf8v v; } tmp;
        if (rok) {
            uint4 u = *(const uint4*)(xh + (size_t)row * 256 + k0);
            f4v s0 = *(const f4v*)(ss1 + k0);
            f4v s1 = *(const f4v*)(ss1 + k0 + 4);
            f4v h0 = *(const f4v*)(ss1 + 256 + k0);
            f4v h1 = *(const f4v*)(ss1 + 256 + k0 + 4);
            float f[8];
            f2v p;
            p = bfpair(u.x); f[0] = p.x; f[1] = p.y;
            p = bfpair(u.y); f[2] = p.x; f[3] = p.y;
            p = bfpair(u.z); f[4] = p.x; f[5] = p.y;
            p = bfpair(u.w); f[6] = p.x; f[7] = p.y;
            float scv[8] = {s0.x, s0.y, s0.z, s0.w, s1.x, s1.y, s1.z, s1.w};
            float shv[8] = {h0.x, h0.y, h0.z, h0.w, h1.x, h1.y, h1.z, h1.w};
            #pragma unroll
            for (int j = 0; j < 8; j++) {
                float v = f[j] * scv[j] + shv[j];
                v = v > 0.f ? v : 0.f;
                tmp.hh[j] = f2bf(v);
            }
        } else {
            tmp.u = (uint4){0u, 0u, 0u, 0u};
        }
        a[kc] = tmp.v;
    }

    f4v acc[16];
    #pragma unroll
    for (int t = 0; t < 16; t++) acc[t] = (f4v){0.f, 0.f, 0.f, 0.f};

    for (int kc = 0; kc < 8; kc++) {
        __syncthreads();                 // staging of buf kc&1 done; prev buf free
        if (kc < 7) stage((kc + 1) & 1, kc + 1);
        const unsigned short* bb2 = &Bs[kc & 1][h * 16][lane * 8];
        #pragma unroll
        for (int t = 0; t < 16; t++) {
            bf8v b = *reinterpret_cast<const bf8v*>(bb2 + t * 512);
            // swapped operands: acc[t] = C^T fragment
            acc[t] = __builtin_amdgcn_mfma_f32_16x16x32_bf16(b, a[kc], acc[t], 0, 0, 0);
        }
    }

    // ---- C^T epilogue: lane owns node row (lane&15), cols q*4..q*4+3 within each t ----
    int q = lane >> 4;
    unsigned short* outp = cv ? (h ? xrB : xlB) : (h ? xrA : xlA);
    const float* bias = cv ? (h ? br1 : bl1) : (h ? br0 : bl0);
    if (rok) {
        unsigned short* orow = outp + (size_t)row * 256 + q * 4;
        #pragma unroll
        for (int t = 0; t < 16; t++) {
            f4v bv = *(const f4v*)(bias + t * 16 + q * 4);
            uint2 u;
            u.x = f2bf2(acc[t][0] + bv.x, acc[t][1] + bv.y);
            u.y = f2bf2(acc[t][2] + bv.z, acc[t][3] + bv.w);
            *reinterpret_cast<uint2*>(orow + t * 16) = u;
        }
    }
}

// ---------------- fused GATv2 edge phase (concat conv1), persistent waves ----------
// 2048 blocks x 4 waves; each wave grid-strides nodes (stride 8192). Per node:
// TWO edge streams (lanes 0-31 even, 32-63 odd), NO-MAX softmax, 2-deep pipeline.
// Bias loaded at write time (keeps held registers low).
__global__ __launch_bounds__(256) void agg_concat(
        const unsigned short* __restrict__ xl, const unsigned short* __restrict__ xr,
        const float* __restrict__ We, const float* __restrict__ att,
        const int* __restrict__ offsets, const int2* __restrict__ sep,
        const float* __restrict__ bias,
        unsigned short* __restrict__ outh) {
    int gw = blockIdx.x * 4 + (threadIdx.x >> 6);
    int lane = threadIdx.x & 63;
    int half = lane >> 5;
    int sub  = lane & 31;
    int cb   = (sub >> 4) * 128 + (sub & 15) * 8;
    f2v wv[4], av[4];
    {
        f4v t0 = *(const f4v*)(We + cb);
        f4v t1 = *(const f4v*)(We + cb + 4);
        wv[0] = (f2v){t0.x, t0.y}; wv[1] = (f2v){t0.z, t0.w};
        wv[2] = (f2v){t1.x, t1.y}; wv[3] = (f2v){t1.z, t1.w};
        t0 = *(const f4v*)(att + cb);
        t1 = *(const f4v*)(att + cb + 4);
        av[0] = (f2v){t0.x, t0.y}; av[1] = (f2v){t0.z, t0.w};
        av[2] = (f2v){t1.x, t1.y}; av[3] = (f2v){t1.z, t1.w};
    }
    int n = gw;
    int beg = 0, end = 0;
    if (n < N_NODES) { beg = offsets[n]; end = offsets[n + 1]; }
    while (n < N_NODES) {
        int nn = n + AGG_STRIDE;
        int nbeg = 0, nend = 0;
        if (nn < N_NODES) { nbeg = offsets[nn]; nend = offsets[nn + 1]; }  // prefetch
        uint4 r8 = *(const uint4*)(xr + ((size_t)n << 8) + cb);
        f2v rv[4];
        rv[0] = bfpair(r8.x); rv[1] = bfpair(r8.y);
        rv[2] = bfpair(r8.z); rv[3] = bfpair(r8.w);

        float den = 0.f;
        f2v acc[4];
        #pragma unroll
        for (int j = 0; j < 4; j++) acc[j] = (f2v){0.f, 0.f};

        int i = beg + half;
        float wN = 0.f;
        int2 seP = make_int2(0, 0);
        uint4 lN = {0u, 0u, 0u, 0u};
        if (i < end) {
            int2 se = sep[i];
            wN = __int_as_float(se.y);
            lN = *(const uint4*)(xl + ((size_t)se.x << 8) + cb);
        }
        if (i + 2 < end) seP = sep[i + 2];
        for (; i < end; i += 2) {
            uint4 l8 = lN; float w = wN;
            if (i + 2 < end) {                           // gather uses pre-fetched index
                lN = *(const uint4*)(xl + ((size_t)seP.x << 8) + cb);
                wN = __int_as_float(seP.y);
            }
            if (i + 4 < end) seP = sep[i + 4];
            f2v w2 = (f2v){w, w};
            f2v lv[4];
            lv[0] = bfpair(l8.x); lv[1] = bfpair(l8.y);
            lv[2] = bfpair(l8.z); lv[3] = bfpair(l8.w);
            f2v da = (f2v){0.f, 0.f};
            #pragma unroll
            for (int j = 0; j < 4; j++) {
                f2v v = lv[j] + rv[j] + w2 * wv[j];
                f2v s = v * (f2v){NEG_SLOPE, NEG_SLOPE};
                v.x = fmaxf(v.x, s.x); v.y = fmaxf(v.y, s.y);   // leaky relu
                da += v * av[j];
            }
            float a = da.x + da.y;
            a += __shfl_xor(a, 1, 64);
            a += __shfl_xor(a, 2, 64);
            a += __shfl_xor(a, 4, 64);
            a += __shfl_xor(a, 8, 64);                   // per-head alpha (16-lane groups)
            float p = __expf(a);
            den += p;
            f2v p2 = (f2v){p, p};
            #pragma unroll
            for (int j = 0; j < 4; j++) acc[j] += p2 * lv[j];
        }
        // merge even/odd streams (pure adds)
        den += __shfl_xor(den, 32, 64);
        #pragma unroll
        for (int j = 0; j < 4; j++) {
            f2v ao;
            ao.x = __shfl_xor(acc[j].x, 32, 64);
            ao.y = __shfl_xor(acc[j].y, 32, 64);
            acc[j] += ao;
        }
        float inv = 1.f / (den + 1e-16f);
        if (lane < 32) {
            f4v b0 = *(const f4v*)(bias + cb);
            f4v b1 = *(const f4v*)(bias + cb + 4);
            union { unsigned short hh[8]; uint4 u; } o;
            o.hh[0] = f2bf(acc[0].x * inv + b0.x);
            o.hh[1] = f2bf(acc[0].y * inv + b0.y);
            o.hh[2] = f2bf(acc[1].x * inv + b0.z);
            o.hh[3] = f2bf(acc[1].y * inv + b0.w);
            o.hh[4] = f2bf(acc[2].x * inv + b1.x);
            o.hh[5] = f2bf(acc[2].y * inv + b1.y);
            o.hh[6] = f2bf(acc[3].x * inv + b1.z);
            o.hh[7] = f2bf(acc[3].y * inv + b1.w);
            *(uint4*)(outh + (size_t)n * 256 + cb) = o.u;
        }
        n = nn; beg = nbeg; end = nend;
    }
}

// ---------------- fused DUAL GATv2 edge phase (mu + log_std), persistent waves ----------
// CONV-PER-LANE-HALF: lanes 0-31 own conv A (mu), lanes 32-63 own conv B (ls).
// Single shared edge stream; one gather instruction covers both tables; the
// shfl alpha-reduce serves both convs at once. Per-lane state halved (~50 regs).
// NATURAL register allocation (R6's forced (256,8) caused catastrophic spills).
__global__ __launch_bounds__(256) void agg_dual(
        const unsigned short* __restrict__ xlA, const unsigned short* __restrict__ xrA,
        const unsigned short* __restrict__ xlB, const unsigned short* __restrict__ xrB,
        const float* __restrict__ WeA, const float* __restrict__ attA,
        const float* __restrict__ WeB, const float* __restrict__ attB,
        const int* __restrict__ offsets, const int2* __restrict__ sep,
        const float* __restrict__ biasA, const float* __restrict__ biasB,
        float* __restrict__ outA, float* __restrict__ outB) {
    int gw = blockIdx.x * 4 + (threadIdx.x >> 6);
    int lane = threadIdx.x & 63;
    int sub  = lane & 31;
    int cb   = (sub >> 4) * 128 + (sub & 15) * 8;   // channel base within conv
    int c0   = (lane & 15) * 8;
    int convB = lane >> 5;                           // 0 = mu, 1 = ls
    const unsigned short* xlp = (convB ? xlB : xlA) + cb;
    const unsigned short* xrp = (convB ? xrB : xrA) + cb;
    const float* Wep  = convB ? WeB : WeA;
    const float* attp = convB ? attB : attA;
    f2v wv[4], av[4];
    {
        f4v t0 = *(const f4v*)(Wep + cb);
        f4v t1 = *(const f4v*)(Wep + cb + 4);
        wv[0] = (f2v){t0.x, t0.y}; wv[1] = (f2v){t0.z, t0.w};
        wv[2] = (f2v){t1.x, t1.y}; wv[3] = (f2v){t1.z, t1.w};
        t0 = *(const f4v*)(attp + cb);
        t1 = *(const f4v*)(attp + cb + 4);
        av[0] = (f2v){t0.x, t0.y}; av[1] = (f2v){t0.z, t0.w};
        av[2] = (f2v){t1.x, t1.y}; av[3] = (f2v){t1.z, t1.w};
    }
    int n = gw;
    int beg = 0, end = 0;
    if (n < N_NODES) { beg = offsets[n]; end = offsets[n + 1]; }
    while (n < N_NODES) {
        int nn = n + AGG_STRIDE;
        int nbeg = 0, nend = 0;
        if (nn < N_NODES) { nbeg = offsets[nn]; nend = offsets[nn + 1]; }  // prefetch
        uint4 r8 = *(const uint4*)(xrp + ((size_t)n << 8));
        f2v rv[4];
        rv[0] = bfpair(r8.x); rv[1] = bfpair(r8.y);
        rv[2] = bfpair(r8.z); rv[3] = bfpair(r8.w);

        float den = 0.f;
        f2v acc[4];
        #pragma unroll
        for (int j = 0; j < 4; j++) acc[j] = (f2v){0.f, 0.f};

        int i = beg;
        float wN = 0.f, wP = 0.f;
        int sP = 0;
        uint4 lN = {0u, 0u, 0u, 0u};
        if (i < end) {
            int2 se = sep[i];
            wN = __int_as_float(se.y);
            lN = *(const uint4*)(xlp + ((size_t)se.x << 8));
        }
        if (i + 1 < end) { int2 se = sep[i + 1]; sP = se.x; wP = __int_as_float(se.y); }
        for (; i < end; ++i) {
            uint4 l8 = lN; float w = wN;
            if (i + 1 < end) {                           // gather uses pre-fetched index
                lN = *(const uint4*)(xlp + ((size_t)sP << 8));
                wN = wP;
            }
            if (i + 2 < end) { int2 se = sep[i + 2]; sP = se.x; wP = __int_as_float(se.y); }
            f2v w2 = (f2v){w, w};
            f2v lv[4];
            lv[0] = bfpair(l8.x); lv[1] = bfpair(l8.y);
            lv[2] = bfpair(l8.z); lv[3] = bfpair(l8.w);
            f2v da = (f2v){0.f, 0.f};
            #pragma unroll
            for (int j = 0; j < 4; j++) {
                f2v v = lv[j] + rv[j] + w2 * wv[j];
                f2v s = v * (f2v){NEG_SLOPE, NEG_SLOPE};
                v.x = fmaxf(v.x, s.x); v.y = fmaxf(v.y, s.y);   // leaky relu
                da += v * av[j];
            }
            float a = da.x + da.y;
            a += __shfl_xor(a, 1, 64);
            a += __shfl_xor(a, 2, 64);
            a += __shfl_xor(a, 4, 64);
            a += __shfl_xor(a, 8, 64);           // per-(conv,head) alpha (16-lane groups)
            float p = __expf(a);
            den += p;
            f2v p2 = (f2v){p, p};
            #pragma unroll
            for (int j = 0; j < 4; j++) acc[j] += p2 * lv[j];
        }
        float inv = 1.f / (den + 1e-16f);
        float o[8], po[8];
        #pragma unroll
        for (int j = 0; j < 4; j++) {
            o[2*j]   = acc[j].x * inv;
            o[2*j+1] = acc[j].y * inv;
        }
        #pragma unroll
        for (int j = 0; j < 8; j++) po[j] = __shfl_xor(o[j], 16, 64);  // other head
        int q = lane >> 4;
        if (q == 0) {                              // lanes 0-15 write conv A (mu)
            f4v b0 = *(const f4v*)(biasA + c0);
            f4v b1 = *(const f4v*)(biasA + c0 + 4);
            float r[8];
            r[0] = (o[0]+po[0])*0.5f + b0.x; r[1] = (o[1]+po[1])*0.5f + b0.y;
            r[2] = (o[2]+po[2])*0.5f + b0.z; r[3] = (o[3]+po[3])*0.5f + b0.w;
            r[4] = (o[4]+po[4])*0.5f + b1.x; r[5] = (o[5]+po[5])*0.5f + b1.y;
            r[6] = (o[6]+po[6])*0.5f + b1.z; r[7] = (o[7]+po[7])*0.5f + b1.w;
            *(float4*)(outA + (size_t)n * 128 + c0)     = *(float4*)&r[0];
            *(float4*)(outA + (size_t)n * 128 + c0 + 4) = *(float4*)&r[4];
        } else if (q == 2) {                       // lanes 32-47 write conv B (log_std)
            f4v b0 = *(const f4v*)(biasB + c0);
            f4v b1 = *(const f4v*)(biasB + c0 + 4);
            float r[8];
            r[0] = (o[0]+po[0])*0.5f + b0.x; r[1] = (o[1]+po[1])*0.5f + b0.y;
            r[2] = (o[2]+po[2])*0.5f + b0.z; r[3] = (o[3]+po[3])*0.5f + b0.w;
            r[4] = (o[4]+po[4])*0.5f + b1.x; r[5] = (o[5]+po[5])*0.5f + b1.y;
            r[6] = (o[6]+po[6])*0.5f + b1.z; r[7] = (o[7]+po[7])*0.5f + b1.w;
            *(float4*)(outB + (size_t)n * 128 + c0)     = *(float4*)&r[0];
            *(float4*)(outB + (size_t)n * 128 + c0 + 4) = *(float4*)&r[4];
        }
        n = nn; beg = nbeg; end = nend;
    }
}

// ---------------- BN1 stats, phase 1: per-block partials (bf16 input, NO atomics) --------
__global__ void bn1_reduce(const unsigned short* __restrict__ xh, float* __restrict__ part) {
    __shared__ float lds[256][9];   // stride 9 floats -> no bank conflicts
    int tid = threadIdx.x;
    int cg = tid & 63;              // col group: cols cg*4 .. cg*4+3
    int ph = tid >> 6;              // row phase 0..3
    int r0 = blockIdx.x * 96;
    float s[4] = {0,0,0,0}, q[4] = {0,0,0,0};
    #pragma unroll
    for (int it = 0; it < 24; it++) {
        int row = r0 + it * 4 + ph;
        if (row < N_NODES) {
            uint2 v = *(const uint2*)(xh + (size_t)row * 256 + cg * 4);
            f2v p0 = bfpair(v.x), p1 = bfpair(v.y);
            s[0] += p0.x; s[1] += p0.y; s[2] += p1.x; s[3] += p1.y;
            q[0] += p0.x*p0.x; q[1] += p0.y*p0.y; q[2] += p1.x*p1.x; q[3] += p1.y*p1.y;
        }
    }
    #pragma unroll
    for (int j = 0; j < 4; j++) { lds[tid][j] = s[j]; lds[tid][4+j] = q[j]; }
    __syncthreads();
    if (tid < 64) {
        float4 sv, qv;
        float* svp = (float*)&sv; float* qvp = (float*)&qv;
        #pragma unroll
        for (int j = 0; j < 4; j++) {
            svp[j] = lds[tid][j] + lds[tid+64][j] + lds[tid+128][j] + lds[tid+192][j];
            qvp[j] = lds[tid][4+j] + lds[tid+64][4+j] + lds[tid+128][4+j] + lds[tid+192][4+j];
        }
        *(float4*)(part + (size_t)blockIdx.x * 512 + cg * 4) = sv;
        *(float4*)(part + (size_t)blockIdx.x * 512 + 256 + cg * 4) = qv;
    }
}

__global__ void bn1_finalize(const float* __restrict__ part, const float* __restrict__ g,
                             const float* __restrict__ b, float* __restrict__ ss1) {
    __shared__ float lds[8][64];
    int t = threadIdx.x;
    int c = blockIdx.x * 32 + (t & 31);
    int ph = t >> 5;                 // 0..7
    float s = 0.f, q = 0.f;
    for (int bi = ph; bi < BN1_BLOCKS; bi += 8) {
        s += part[(size_t)bi * 512 + c];
        q += part[(size_t)bi * 512 + 256 + c];
    }
    lds[ph][t & 31] = s;
    lds[ph][32 + (t & 31)] = q;
    __syncthreads();
    if (t < 32) {
        float ss = 0.f, qq = 0.f;
        #pragma unroll
        for (int p = 0; p < 8; p++) { ss += lds[p][t]; qq += lds[p][32 + t]; }
        float mean = ss * (1.f / N_NODES);
        float var  = qq * (1.f / N_NODES) - mean * mean;
        float sc = g[c] * rsqrtf(var + BN_EPS);
        ss1[c] = sc;
        ss1[256 + c] = b[c] - mean * sc;
    }
}

extern "C" void kernel_launch(void* const* d_in, const int* in_sizes, int n_in,
                              void* d_out, int out_size, void* d_ws, size_t ws_size,
                              hipStream_t stream) {
    const float* h          = (const float*)d_in[0];
    const int*   edge_index = (const int*)d_in[1];
    const int*   src = edge_index;
    const int*   dst = edge_index + N_EDGES;
    const float* ew   = (const float*)d_in[2];
    const float* bn0g = (const float*)d_in[3];
    const float* bn0b = (const float*)d_in[4];
    const float* bn1g = (const float*)d_in[5];
    const float* bn1b = (const float*)d_in[6];
    const float* c1_Wl = (const float*)d_in[7];
    const float* c1_bl = (const float*)d_in[8];
    const float* c1_Wr = (const float*)d_in[9];
    const float* c1_br = (const float*)d_in[10];
    const float* c1_We = (const float*)d_in[11];
    const float* c1_att = (const float*)d_in[12];
    const float* c1_bias = (const float*)d_in[13];
    const float* mu_Wl = (const float*)d_in[14];
    const float* mu_bl = (const float*)d_in[15];
    const float* mu_Wr = (const float*)d_in[16];
    const float* mu_br = (const float*)d_in[17];
    const float* mu_We = (const float*)d_in[18];
    const float* mu_att = (const float*)d_in[19];
    const float* mu_bias = (const float*)d_in[20];
    const float* ls_Wl = (const float*)d_in[21];
    const float* ls_bl = (const float*)d_in[22];
    const float* ls_Wr = (const float*)d_in[23];
    const float* ls_br = (const float*)d_in[24];
    const float* ls_We = (const float*)d_in[25];
    const float* ls_att = (const float*)d_in[26];
    const float* ls_bias = (const float*)d_in[27];

    float* out_mu = (float*)d_out;
    float* out_ls = (float*)d_out + (size_t)N_NODES * 128;

    // workspace carve-up (256B aligned blocks)
    char* ws = (char*)d_ws;
    size_t off = 0;
    auto alloc = [&](size_t bytes) -> void* {
        void* p = ws + off;
        off += (bytes + 255) / 256 * 256;
        return p;
    };
    unsigned short* xl  = (unsigned short*)alloc((size_t)N_NODES * 256 * 2);
    unsigned short* xr  = (unsigned short*)alloc((size_t)N_NODES * 256 * 2);
    unsigned short* xBh = (unsigned short*)alloc((size_t)N_NODES * 256 * 2);  // bf16 conv1 out
    unsigned short* xl2 = (unsigned short*)alloc((size_t)N_NODES * 256 * 2);
    unsigned short* xr2 = (unsigned short*)alloc((size_t)N_NODES * 256 * 2);
    float* bn0acc  = (float*)alloc(10 * 4);
    float* bn1part = (float*)alloc((size_t)BN1_BLOCKS * 512 * 4);   // 1.07 MB
    float* bn1ss   = (float*)alloc(512 * 4);
    int*   count   = (int*)alloc((size_t)N_NODES * 4);
    int*   offsets = (int*)alloc((size_t)(N_NODES + 1) * 4);
    int*   cursor  = (int*)alloc((size_t)N_NODES * 4);
    int2*  sep     = (int2*)alloc((size_t)N_EDGES * 8);
    int*   tileSum = (int*)alloc((size_t)SCAN_TILES * 4);
    unsigned short* Bpack = (unsigned short*)alloc((size_t)2 * 131072 * 2);   // 512 KB

    hipMemsetAsync(count, 0, (size_t)N_NODES * 4, stream);
    hipMemsetAsync(bn0acc, 0, 10 * 4, stream);

    // fused: BN0 stats | edge histogram | pack mu/ls weights
    prep<<<PREP_BN0 + PREP_EC + PREP_PW, 256, 0, stream>>>(
        h, bn0acc, dst, count, mu_Wl, mu_Wr, ls_Wl, ls_Wr, Bpack);

    // CSR by dst — two-level scan (wave-shfl local scan, fused tile prefix)
    local_scan<<<SCAN_TILES, 1024, 0, stream>>>(count, offsets, tileSum);
    add_prefix<<<SCAN_TILES, 1024, 0, stream>>>(offsets, tileSum, cursor);
    edge_scatter<<<(N_EDGES + 255) / 256, 256, 0, stream>>>(dst, src, ew, cursor, sep);

    // conv1 (concat) with fused BN0 finalize+apply, reg-resident weights
    gemm_k5<<<K5_BLOCKS, 128, 0, stream>>>(h, bn0acc, bn0g, bn0b,
                                           c1_Wl, c1_bl, c1_Wr, c1_br, xl, xr);
    agg_concat<<<AGG_BLOCKS, 256, 0, stream>>>(xl, xr, c1_We, c1_att, offsets,
                                               sep, c1_bias, xBh);

    // BN1 stats (atomic-free two-phase); apply+ReLU fused into gemm_mfma A-load
    bn1_reduce<<<BN1_BLOCKS, 256, 0, stream>>>(xBh, bn1part);
    bn1_finalize<<<8, 256, 0, stream>>>(bn1part, bn1g, bn1b, bn1ss);

    // mu and log_std linears: one conv per block (grid 1564), fused BN1+ReLU A-load,
    // operand-swapped MFMA -> coalesced 8B C-stores
    gemm_mfma<<<1564, 512, 0, stream>>>(xBh, bn1ss, Bpack,
                                        mu_bl, mu_br, ls_bl, ls_br,
                                        xl, xr, xl2, xr2);

    // fused dual aggregation (mu + log_std, conv-per-lane-half, natural regs)
    agg_dual<<<AGG_BLOCKS, 256, 0, stream>>>(xl, xr, xl2, xr2,
                                             mu_We, mu_att, ls_We, ls_att,
                                             offsets, sep,
                                             mu_bias, ls_bias, out_mu, out_ls);
}